// Round 2
// baseline (1251.878 us; speedup 1.0000x reference)
//
#include <hip/hip_runtime.h>

// ---------------------------------------------------------------------------
// QuantizedAttention (B=8, S=2048, E=1024), no head split: scores are [B,S,S].
//   amax(inputs, weights) -> quant weights bf16-int
//   k_proj: on-the-fly quant of inputs, exact bf16-int MFMA GEMM,
//           epilogue -> q,k as fp16 hi/lo planes, v fp16
//   k_transpose: v -> vT [B][E][S] fp16, stored in d_out (scratch until final)
//   per batch: scores = (qh+ql)@(kh+kl)^T * 0.125 (3-term fp16 MFMA, f32 acc)
//              row softmax f32 -> unnormalized P fp16 + 1/rowsum
//   per batch-pair: PV 128^2-tile GEMM -> attn_out fp16 (+ f32 amax atomics)
//   quant attn_out -> bf16-int -> exact MFMA final proj -> d_out f32
// Peak workspace ~200.03 MiB; if ws_size is smaller, writes zeros to d_out
// (clean diagnostic failure instead of a memory fault).
// ---------------------------------------------------------------------------

typedef __attribute__((ext_vector_type(4))) float f32x4;
typedef __attribute__((ext_vector_type(8))) short bf16x8;
typedef __attribute__((ext_vector_type(8))) unsigned short u16x8;
typedef _Float16 f16;
typedef _Float16 half8 __attribute__((ext_vector_type(8)));
typedef _Float16 half4 __attribute__((ext_vector_type(4)));

#define DEVI static __device__ __forceinline__

constexpr int B_ = 8, S_ = 2048, E_ = 1024;
constexpr long NROW = (long)B_ * S_;  // 16384

constexpr size_t KB = 1024, MB = 1024 * 1024;
constexpr size_t OFF_SC  = 0;                       // u32[8] amax bits
constexpr size_t OFF_RS  = 1 * KB;                  // 4096 f32 recip rowsums (2 batches)
constexpr size_t OFF_W   = 32 * KB;                 // 4 weight planes bf16-int
constexpr size_t SZ_WPL  = (size_t)E_ * E_ * 2;     // 2 MiB
constexpr size_t SZ_PL   = (size_t)NROW * E_ * 2;   // 32 MiB
constexpr size_t OFF_QH  = OFF_W + 4 * SZ_WPL;
constexpr size_t OFF_QL  = OFF_QH + SZ_PL;
constexpr size_t OFF_KH  = OFF_QL + SZ_PL;
constexpr size_t OFF_KL  = OFF_KH + SZ_PL;
constexpr size_t OFF_VH  = OFF_KL + SZ_PL;          // later overlay: attn_out fp16
constexpr size_t OFF_SCB = OFF_VH + SZ_PL;          // scores f32, one batch, 16 MiB
constexpr size_t OFF_PB  = OFF_SCB + 16 * MB;       // P fp16, two batches, 16 MiB
constexpr size_t WS_NEED = OFF_PB + 16 * MB;        // ~200.03 MiB
constexpr size_t OFF_AOQ = OFF_SCB;                 // quantized attn_out bf16 (32 MiB overlay)

// ---- helpers ---------------------------------------------------------------
typedef const __attribute__((address_space(1))) void* gptr1;
typedef __attribute__((address_space(3))) void* lptr3;

DEVI void gload16(const void* g, void* l) {
  __builtin_amdgcn_global_load_lds((gptr1)g, (lptr3)l, 16, 0, 0);
}

DEVI f32x4 MF(bf16x8 a, bf16x8 b, f32x4 c) {
  return __builtin_amdgcn_mfma_f32_16x16x32_bf16(a, b, c, 0, 0, 0);
}
DEVI f32x4 MF(half8 a, half8 b, f32x4 c) {
  return __builtin_amdgcn_mfma_f32_16x16x32_f16(a, b, c, 0, 0, 0);
}

DEVI float scale_of(const unsigned int* amaxU, int idx) {
  return fmaxf(__uint_as_float(amaxU[idx]) / 127.f, 1e-8f);
}

// quantize to integer-valued bf16 (|int|<=127 is exact in bf16)
DEVI unsigned short qbf(float x, float rs) {
  float q = fminf(fmaxf(rintf(x * rs), -127.f), 127.f);
  return (unsigned short)(__float_as_uint(q) >> 16);
}

// ---- small kernels ---------------------------------------------------------
__global__ void k_zero(float* o, long n) {
  long i = ((long)blockIdx.x * blockDim.x + threadIdx.x) * 4;
  const long stride = (long)gridDim.x * blockDim.x * 4;
  for (; i < n; i += stride) {
    float4 z = {0.f, 0.f, 0.f, 0.f};
    *(float4*)(o + i) = z;
  }
}

__global__ void k_init(unsigned int* a) {
  if (threadIdx.x < 8) a[threadIdx.x] = 0u;
}

__global__ void k_amax(const float* __restrict__ x, long n, unsigned int* amaxU, int idx) {
  long i = ((long)blockIdx.x * blockDim.x + threadIdx.x) * 4;
  const long stride = (long)gridDim.x * blockDim.x * 4;
  float m = 0.f;
  for (; i < n; i += stride) {
    float4 v = *(const float4*)(x + i);
    m = fmaxf(m, fmaxf(fmaxf(fabsf(v.x), fabsf(v.y)), fmaxf(fabsf(v.z), fabsf(v.w))));
  }
#pragma unroll
  for (int o = 32; o; o >>= 1) m = fmaxf(m, __shfl_xor(m, o));
  if ((threadIdx.x & 63) == 0) atomicMax(amaxU + idx, __float_as_uint(m));
}

__global__ void k_quant(const float* __restrict__ x, unsigned short* __restrict__ q, long n,
                        const unsigned int* __restrict__ amaxU, int idx) {
  const float rs = 1.f / scale_of(amaxU, idx);
  long i = ((long)blockIdx.x * blockDim.x + threadIdx.x) * 4;
  const long stride = (long)gridDim.x * blockDim.x * 4;
  for (; i < n; i += stride) {
    float4 v = *(const float4*)(x + i);
    short4 o;
    o.x = (short)qbf(v.x, rs);
    o.y = (short)qbf(v.y, rs);
    o.z = (short)qbf(v.z, rs);
    o.w = (short)qbf(v.w, rs);
    *(short4*)(q + i) = o;
  }
}

// ---- shared GEMM core: C(128x128) = A(128xK) @ B(128xK)^T ------------------
template <typename VEC>
DEVI void gemm_core(const unsigned short* __restrict__ A, const unsigned short* __restrict__ Bm,
                    int lda, int ldb, int K,
                    unsigned short* ldsA, unsigned short* ldsB, f32x4 acc[4][4], int tid) {
  const int lane = tid & 63;
  const int wid = tid >> 6;
  const int wm = wid >> 1, wn = wid & 1;
  const int frow = lane & 15;
  const int fko = (lane >> 4) * 8;
  for (int k0 = 0; k0 < K; k0 += 64) {
    __syncthreads();
#pragma unroll
    for (int it = 0; it < 4; ++it) {
      int c = it * 256 + tid;
      int row = c >> 3;
      int cc = c & 7;
      int lb = (it * 256 + (tid & 192)) * 8;  // wave-uniform LDS base (elements)
      gload16(A + (long)row * lda + k0 + cc * 8, ldsA + lb);
      gload16(Bm + (long)row * ldb + k0 + cc * 8, ldsB + lb);
    }
    __syncthreads();
#pragma unroll
    for (int kc = 0; kc < 2; ++kc) {
      VEC a[4], b[4];
#pragma unroll
      for (int m = 0; m < 4; ++m)
        a[m] = *(const VEC*)(ldsA + (wm * 64 + m * 16 + frow) * 64 + kc * 32 + fko);
#pragma unroll
      for (int n = 0; n < 4; ++n)
        b[n] = *(const VEC*)(ldsB + (wn * 64 + n * 16 + frow) * 64 + kc * 32 + fko);
#pragma unroll
      for (int m = 0; m < 4; ++m)
#pragma unroll
        for (int n = 0; n < 4; ++n)
          acc[m][n] = MF(a[m], b[n], acc[m][n]);
    }
  }
}

// ---- projections: on-the-fly input quant + exact int bf16 GEMM -------------
__global__ __launch_bounds__(256, 2) void k_proj(char* __restrict__ ws,
                                                 const float* __restrict__ qin,
                                                 const float* __restrict__ kin,
                                                 const float* __restrict__ vin,
                                                 const float* __restrict__ bq,
                                                 const float* __restrict__ bk,
                                                 const float* __restrict__ bv) {
  __shared__ __attribute__((aligned(16))) unsigned short lA[128 * 64], lB[128 * 64];
  const int tid = threadIdx.x;
  const int z = blockIdx.z;
  const unsigned int* amaxU = (const unsigned int*)(ws + OFF_SC);
  const float* Af = ((z == 0) ? qin : ((z == 1) ? kin : vin)) + (size_t)blockIdx.y * 128 * E_;
  const unsigned short* Bm =
      (const unsigned short*)(ws + OFF_W + (size_t)z * SZ_WPL) + (size_t)blockIdx.x * 128 * E_;
  f16* H = (f16*)(ws + OFF_QH + (size_t)z * 2 * SZ_PL);  // z: 0->QH 1->KH 2->VH
  f16* L = (f16*)((char*)H + SZ_PL);
  const float* bias = (z == 0) ? bq : ((z == 1) ? bk : bv);
  const float s_in = scale_of(amaxU, z);
  const float rs_in = 1.f / s_in;
  const float sc = s_in * scale_of(amaxU, 3 + z);
  const int lane = tid & 63, wid = tid >> 6, wm = wid >> 1, wn = wid & 1;
  const int frow = lane & 15, fko = (lane >> 4) * 8;
  f32x4 acc[4][4] = {};
  for (int k0 = 0; k0 < E_; k0 += 64) {
    __syncthreads();
#pragma unroll
    for (int it = 0; it < 4; ++it) {  // B: weights, already bf16-int
      int c = it * 256 + tid;
      int lb = (it * 256 + (tid & 192)) * 8;
      gload16(Bm + (long)(c >> 3) * E_ + k0 + (c & 7) * 8, lB + lb);
    }
#pragma unroll
    for (int it = 0; it < 4; ++it) {  // A: f32 input -> int bf16 in regs -> LDS
      int c = it * 256 + tid;
      int row = c >> 3, cc = c & 7;
      const float* src = Af + (long)row * E_ + k0 + cc * 8;
      float4 u0 = *(const float4*)src;
      float4 u1 = *(const float4*)(src + 4);
      u16x8 w;
      w[0] = qbf(u0.x, rs_in); w[1] = qbf(u0.y, rs_in);
      w[2] = qbf(u0.z, rs_in); w[3] = qbf(u0.w, rs_in);
      w[4] = qbf(u1.x, rs_in); w[5] = qbf(u1.y, rs_in);
      w[6] = qbf(u1.z, rs_in); w[7] = qbf(u1.w, rs_in);
      *(u16x8*)(lA + c * 8) = w;
    }
    __syncthreads();
#pragma unroll
    for (int kc = 0; kc < 2; ++kc) {
      bf16x8 a[4], b[4];
#pragma unroll
      for (int m = 0; m < 4; ++m)
        a[m] = *(const bf16x8*)(lA + (wm * 64 + m * 16 + frow) * 64 + kc * 32 + fko);
#pragma unroll
      for (int n = 0; n < 4; ++n)
        b[n] = *(const bf16x8*)(lB + (wn * 64 + n * 16 + frow) * 64 + kc * 32 + fko);
#pragma unroll
      for (int m = 0; m < 4; ++m)
#pragma unroll
        for (int n = 0; n < 4; ++n)
          acc[m][n] = MF(a[m], b[n], acc[m][n]);
    }
  }
  const long r0 = (long)blockIdx.y * 128 + wm * 64;
  const int c0 = blockIdx.x * 128 + wn * 64;
  const bool has_lo = (z < 2);
#pragma unroll
  for (int m = 0; m < 4; ++m)
#pragma unroll
    for (int n = 0; n < 4; ++n) {
      int col = c0 + n * 16 + (lane & 15);
      float bc = bias[col];
#pragma unroll
      for (int r = 0; r < 4; ++r) {
        long row = r0 + m * 16 + (lane >> 4) * 4 + r;
        float y = sc * acc[m][n][r] + bc;
        f16 h = (f16)y;
        H[row * E_ + col] = h;
        if (has_lo) L[row * E_ + col] = (f16)(y - (float)h);
      }
    }
}

// ---- V transpose: vh [b][s][e] (ws) -> vT [b][e][s] (d_out scratch) --------
__global__ void k_transpose(const char* __restrict__ ws, f16* __restrict__ vt) {
  __shared__ f16 t[64][72];
  const int b = blockIdx.z, e0 = blockIdx.x * 64, s0 = blockIdx.y * 64;
  const f16* V = (const f16*)(ws + OFF_VH) + (size_t)b * S_ * E_;
  f16* VT = vt + (size_t)b * E_ * S_;
  const int tid = threadIdx.x;
  const int r = tid >> 2, cc = (tid & 3) * 16;
#pragma unroll
  for (int j = 0; j < 2; ++j) {
    half8 v = *(const half8*)(V + (size_t)(s0 + r) * E_ + e0 + cc + j * 8);
#pragma unroll
    for (int q = 0; q < 8; ++q) t[cc + j * 8 + q][r] = v[q];
  }
  __syncthreads();
#pragma unroll
  for (int j = 0; j < 2; ++j) {
    half8 w;
#pragma unroll
    for (int q = 0; q < 8; ++q) w[q] = t[r][cc + j * 8 + q];
    *(half8*)(VT + (size_t)(e0 + r) * S_ + s0 + cc + j * 8) = w;
  }
}

// ---- scores (one batch): C = 0.125 * (qh+ql)@(kh+kl)^T ---------------------
__global__ __launch_bounds__(256, 2) void k_scores(char* __restrict__ ws, int b) {
  __shared__ __attribute__((aligned(16))) unsigned short lAh[128 * 32], lAl[128 * 32],
      lBh[128 * 32], lBl[128 * 32];
  const int tid = threadIdx.x;
  const size_t arow = ((size_t)b * S_ + (size_t)blockIdx.y * 128) * E_;
  const size_t brow = ((size_t)b * S_ + (size_t)blockIdx.x * 128) * E_;
  const f16* Ah = (const f16*)(ws + OFF_QH) + arow;
  const f16* Al = (const f16*)(ws + OFF_QL) + arow;
  const f16* Bh = (const f16*)(ws + OFF_KH) + brow;
  const f16* Bl = (const f16*)(ws + OFF_KL) + brow;
  float* C = (float*)(ws + OFF_SCB);
  const int lane = tid & 63, wid = tid >> 6, wm = wid >> 1, wn = wid & 1;
  const int frow = lane & 15, fko = (lane >> 4) * 8;
  f32x4 acc[4][4] = {};
  for (int k0 = 0; k0 < E_; k0 += 32) {
    __syncthreads();
#pragma unroll
    for (int it = 0; it < 2; ++it) {
      int c = it * 256 + tid;
      int row = c >> 2, cc = c & 3;
      int lb = (it * 256 + (tid & 192)) * 8;
      long go = (long)row * E_ + k0 + cc * 8;
      gload16(Ah + go, lAh + lb);
      gload16(Al + go, lAl + lb);
      gload16(Bh + go, lBh + lb);
      gload16(Bl + go, lBl + lb);
    }
    __syncthreads();
    half8 ah[4], al[4], bh[4], bl[4];
#pragma unroll
    for (int m = 0; m < 4; ++m) {
      int off = (wm * 64 + m * 16 + frow) * 32 + fko;
      ah[m] = *(const half8*)(lAh + off);
      al[m] = *(const half8*)(lAl + off);
    }
#pragma unroll
    for (int n = 0; n < 4; ++n) {
      int off = (wn * 64 + n * 16 + frow) * 32 + fko;
      bh[n] = *(const half8*)(lBh + off);
      bl[n] = *(const half8*)(lBl + off);
    }
#pragma unroll
    for (int m = 0; m < 4; ++m)
#pragma unroll
      for (int n = 0; n < 4; ++n) {
        acc[m][n] = MF(ah[m], bh[n], acc[m][n]);
        acc[m][n] = MF(ah[m], bl[n], acc[m][n]);
        acc[m][n] = MF(al[m], bh[n], acc[m][n]);
      }
  }
  const int r0 = blockIdx.y * 128 + wm * 64;
  const int c0 = blockIdx.x * 128 + wn * 64;
#pragma unroll
  for (int m = 0; m < 4; ++m)
#pragma unroll
    for (int n = 0; n < 4; ++n) {
      int col = c0 + n * 16 + frow;
#pragma unroll
      for (int r = 0; r < 4; ++r) {
        int row = r0 + m * 16 + (lane >> 4) * 4 + r;
        C[(size_t)row * S_ + col] = 0.125f * acc[m][n][r];
      }
    }
}

// ---- row softmax (one batch): scores f32 -> P fp16 (unnorm) + 1/rowsum -----
__global__ __launch_bounds__(256) void k_softmax(char* __restrict__ ws, int pp) {
  const long row = blockIdx.x;
  const float* src = (const float*)(ws + OFF_SCB) + row * S_;
  f16* P = (f16*)(ws + OFF_PB) + (size_t)pp * S_ * S_ + row * S_;
  float* RS = (float*)(ws + OFF_RS) + pp * S_;
  const int tid = threadIdx.x, lane = tid & 63, wid = tid >> 6;
  float4 v0 = ((const float4*)src)[tid];
  float4 v1 = ((const float4*)src)[tid + 256];
  float m = fmaxf(fmaxf(fmaxf(v0.x, v0.y), fmaxf(v0.z, v0.w)),
                  fmaxf(fmaxf(v1.x, v1.y), fmaxf(v1.z, v1.w)));
#pragma unroll
  for (int o = 32; o; o >>= 1) m = fmaxf(m, __shfl_xor(m, o));
  __shared__ float redm[4], reds[4];
  if (lane == 0) redm[wid] = m;
  __syncthreads();
  m = fmaxf(fmaxf(redm[0], redm[1]), fmaxf(redm[2], redm[3]));
  float e0 = expf(v0.x - m), e1 = expf(v0.y - m), e2 = expf(v0.z - m), e3 = expf(v0.w - m);
  float e4 = expf(v1.x - m), e5 = expf(v1.y - m), e6 = expf(v1.z - m), e7 = expf(v1.w - m);
  float s = ((e0 + e1) + (e2 + e3)) + ((e4 + e5) + (e6 + e7));
#pragma unroll
  for (int o = 32; o; o >>= 1) s += __shfl_xor(s, o);
  if (lane == 0) reds[wid] = s;
  __syncthreads();
  s = (reds[0] + reds[1]) + (reds[2] + reds[3]);
  if (tid == 0) RS[row] = 1.f / s;
  half4 p0 = {(f16)e0, (f16)e1, (f16)e2, (f16)e3};
  half4 p1 = {(f16)e4, (f16)e5, (f16)e6, (f16)e7};
  *(half4*)(P + (long)tid * 4) = p0;
  *(half4*)(P + 1024 + (long)tid * 4) = p1;
}

// ---- PV (batch pair): attn_out = (P @ vT^T) * recip -> fp16 + f32 amax -----
__global__ __launch_bounds__(256, 2) void k_pv(char* __restrict__ ws,
                                               const f16* __restrict__ vt, int bb) {
  __shared__ __attribute__((aligned(16))) unsigned short lA[128 * 64], lB[128 * 64];
  const int tid = threadIdx.x;
  const int z = blockIdx.z;
  const int b = bb + z;
  const unsigned short* A = (const unsigned short*)(ws + OFF_PB) + (size_t)z * S_ * S_ +
                            (size_t)blockIdx.y * 128 * S_;
  const unsigned short* Bm = (const unsigned short*)vt + (size_t)b * E_ * S_ +
                             (size_t)blockIdx.x * 128 * S_;
  f32x4 acc[4][4] = {};
  gemm_core<half8>(A, Bm, S_, S_, S_, lA, lB, acc, tid);
  const float* RS = (const float*)(ws + OFF_RS) + z * S_;
  f16* O = (f16*)(ws + OFF_VH) + (size_t)b * S_ * E_;
  unsigned int* amaxU = (unsigned int*)(ws + OFF_SC);
  const int lane = tid & 63, wid = tid >> 6, wm = wid >> 1, wn = wid & 1;
  const int r0 = blockIdx.y * 128 + wm * 64;
  const int c0 = blockIdx.x * 128 + wn * 64;
  float mx = 0.f;
#pragma unroll
  for (int m = 0; m < 4; ++m)
#pragma unroll
    for (int n = 0; n < 4; ++n) {
      int col = c0 + n * 16 + (lane & 15);
#pragma unroll
      for (int r = 0; r < 4; ++r) {
        int row = r0 + m * 16 + (lane >> 4) * 4 + r;
        float o = acc[m][n][r] * RS[row];
        O[(size_t)row * E_ + col] = (f16)o;
        mx = fmaxf(mx, fabsf(o));
      }
    }
#pragma unroll
  for (int o2 = 32; o2; o2 >>= 1) mx = fmaxf(mx, __shfl_xor(mx, o2));
  if (lane == 0) atomicMax(amaxU + 7, __float_as_uint(mx));
}

// ---- quantize attn_out (fp16 -> int bf16) ----------------------------------
__global__ void k_quant_f16(char* __restrict__ ws) {
  const unsigned int* amaxU = (const unsigned int*)(ws + OFF_SC);
  const float rs = 1.f / scale_of(amaxU, 7);
  const f16* x = (const f16*)(ws + OFF_VH);
  unsigned short* o = (unsigned short*)(ws + OFF_AOQ);
  const long n = NROW * E_;
  long i = ((long)blockIdx.x * blockDim.x + threadIdx.x) * 8;
  const long stride = (long)gridDim.x * blockDim.x * 8;
  for (; i < n; i += stride) {
    half8 v = *(const half8*)(x + i);
    u16x8 w;
#pragma unroll
    for (int j = 0; j < 8; ++j) w[j] = qbf((float)v[j], rs);
    *(u16x8*)(o + i) = w;
  }
}

// ---- final projection: exact int bf16 GEMM -> d_out f32 --------------------
__global__ __launch_bounds__(256, 2) void k_final(char* __restrict__ ws,
                                                  const float* __restrict__ bp,
                                                  float* __restrict__ out) {
  __shared__ __attribute__((aligned(16))) unsigned short lA[128 * 64], lB[128 * 64];
  const int tid = threadIdx.x;
  const unsigned int* amaxU = (const unsigned int*)(ws + OFF_SC);
  const unsigned short* A =
      (const unsigned short*)(ws + OFF_AOQ) + (size_t)blockIdx.y * 128 * E_;
  const unsigned short* Bm =
      (const unsigned short*)(ws + OFF_W + 3 * SZ_WPL) + (size_t)blockIdx.x * 128 * E_;
  const float sc = scale_of(amaxU, 7) * scale_of(amaxU, 6);
  f32x4 acc[4][4] = {};
  gemm_core<bf16x8>(A, Bm, E_, E_, E_, lA, lB, acc, tid);
  const int lane = tid & 63, wid = tid >> 6, wm = wid >> 1, wn = wid & 1;
  const long r0 = (long)blockIdx.y * 128 + wm * 64;
  const int c0 = blockIdx.x * 128 + wn * 64;
#pragma unroll
  for (int m = 0; m < 4; ++m)
#pragma unroll
    for (int n = 0; n < 4; ++n) {
      int col = c0 + n * 16 + (lane & 15);
      float bc = bp[col];
#pragma unroll
      for (int r = 0; r < 4; ++r) {
        long row = r0 + m * 16 + (lane >> 4) * 4 + r;
        out[row * E_ + col] = sc * acc[m][n][r] + bc;
      }
    }
}

// ---------------------------------------------------------------------------
extern "C" void kernel_launch(void* const* d_in, const int* in_sizes, int n_in,
                              void* d_out, int out_size, void* d_ws, size_t ws_size,
                              hipStream_t stream) {
  (void)in_sizes; (void)n_in; (void)out_size;
  char* ws = (char*)d_ws;
  const float* query = (const float*)d_in[0];
  const float* key   = (const float*)d_in[1];
  const float* value = (const float*)d_in[2];
  const float* Wq = (const float*)d_in[3];
  const float* bq = (const float*)d_in[4];
  const float* Wk = (const float*)d_in[5];
  const float* bk = (const float*)d_in[6];
  const float* Wv = (const float*)d_in[7];
  const float* bv = (const float*)d_in[8];
  const float* Wp = (const float*)d_in[9];
  const float* bp = (const float*)d_in[10];

  const long nOut = NROW * E_;  // 16,777,216

  if (ws_size < WS_NEED) {  // diagnostic fallback: zeros, no OOB writes
    k_zero<<<dim3(2048), dim3(256), 0, stream>>>((float*)d_out, nOut);
    return;
  }

  unsigned int* amaxU = (unsigned int*)(ws + OFF_SC);
  const long nIn = NROW * E_;
  const long nW = (long)E_ * E_;
  f16* vt = (f16*)d_out;  // d_out doubles as V^T scratch until k_final

  k_init<<<dim3(1), dim3(64), 0, stream>>>(amaxU);

  k_amax<<<dim3(1024), dim3(256), 0, stream>>>(query, nIn, amaxU, 0);
  k_amax<<<dim3(1024), dim3(256), 0, stream>>>(key,   nIn, amaxU, 1);
  k_amax<<<dim3(1024), dim3(256), 0, stream>>>(value, nIn, amaxU, 2);
  k_amax<<<dim3(256),  dim3(256), 0, stream>>>(Wq, nW, amaxU, 3);
  k_amax<<<dim3(256),  dim3(256), 0, stream>>>(Wk, nW, amaxU, 4);
  k_amax<<<dim3(256),  dim3(256), 0, stream>>>(Wv, nW, amaxU, 5);
  k_amax<<<dim3(256),  dim3(256), 0, stream>>>(Wp, nW, amaxU, 6);

  k_quant<<<dim3(256), dim3(256), 0, stream>>>(Wq, (unsigned short*)(ws + OFF_W), nW, amaxU, 3);
  k_quant<<<dim3(256), dim3(256), 0, stream>>>(Wk, (unsigned short*)(ws + OFF_W + SZ_WPL), nW, amaxU, 4);
  k_quant<<<dim3(256), dim3(256), 0, stream>>>(Wv, (unsigned short*)(ws + OFF_W + 2 * SZ_WPL), nW, amaxU, 5);
  k_quant<<<dim3(256), dim3(256), 0, stream>>>(Wp, (unsigned short*)(ws + OFF_W + 3 * SZ_WPL), nW, amaxU, 6);

  k_proj<<<dim3(8, 128, 3), dim3(256), 0, stream>>>(ws, query, key, value, bq, bk, bv);
  k_transpose<<<dim3(16, 32, 8), dim3(256), 0, stream>>>(ws, vt);

  for (int bb = 0; bb < B_; bb += 2) {
    k_scores<<<dim3(16, 16), dim3(256), 0, stream>>>(ws, bb);
    k_softmax<<<dim3(2048), dim3(256), 0, stream>>>(ws, 0);
    k_scores<<<dim3(16, 16), dim3(256), 0, stream>>>(ws, bb + 1);
    k_softmax<<<dim3(2048), dim3(256), 0, stream>>>(ws, 1);
    k_pv<<<dim3(8, 16, 2), dim3(256), 0, stream>>>(ws, vt, bb);
  }

  k_quant_f16<<<dim3(2048), dim3(256), 0, stream>>>(ws);
  k_final<<<dim3(8, 128), dim3(256), 0, stream>>>(ws, bp, (float*)d_out);
}

// Round 3
// 889.981 us; speedup vs baseline: 1.4066x; 1.4066x over previous
//
#include <hip/hip_runtime.h>

// ---------------------------------------------------------------------------
// QuantizedAttention (B=8, S=2048, E=1024), no head split: scores are [B,S,S].
//   amax(inputs, weights) -> quant ALL to int8 (true division = bit-exact ref)
//     q/k/v int8 planes live in d_out (dead until k_final); weights in ws
//   k_proj_i8: exact i8 MFMA GEMM (i32 acc) -> q,k,v fp16 planes
//   k_transpose: v -> vT [B][E][S] fp16
//   per batch: scores = qh@kh^T * 0.125 (fp16 MFMA, f32 acc)
//              row softmax f32 -> unnormalized P fp16 + 1/rowsum
//   per batch-pair: PV fp16 GEMM -> attn_out fp16 (+ f32 amax atomics)
//   quant attn_out -> int8 -> exact i8 MFMA final proj -> d_out f32
// Peak workspace ~164 MiB (known-good envelope is >=200 MiB).
// ---------------------------------------------------------------------------

typedef __attribute__((ext_vector_type(4))) float f32x4;
typedef __attribute__((ext_vector_type(4))) int i32x4;
typedef __attribute__((ext_vector_type(8))) unsigned short u16x8;
typedef __attribute__((ext_vector_type(8))) char s8x8;
typedef _Float16 f16;
typedef _Float16 half8 __attribute__((ext_vector_type(8)));
typedef _Float16 half4 __attribute__((ext_vector_type(4)));

#define DEVI static __device__ __forceinline__

constexpr int B_ = 8, S_ = 2048, E_ = 1024;
constexpr long NROW = (long)B_ * S_;  // 16384

constexpr size_t KB = 1024, MB = 1024 * 1024;
constexpr size_t OFF_SC  = 0;                     // u32[8] amax bits
constexpr size_t OFF_RS  = 1 * KB;                // 4096 f32 recip rowsums (2 batches)
constexpr size_t OFF_W   = 32 * KB;               // 4 weight planes int8, 1 MiB each
constexpr size_t SZ_WPL  = (size_t)E_ * E_;       // 1 MiB
constexpr size_t SZ_PL   = (size_t)NROW * E_ * 2; // 32 MiB (fp16 plane)
constexpr size_t OFF_QH  = OFF_W + 4 * SZ_WPL;
constexpr size_t OFF_KH  = OFF_QH + SZ_PL;
constexpr size_t OFF_VH  = OFF_KH + SZ_PL;        // later overlay: attn_out fp16
constexpr size_t OFF_VT  = OFF_VH + SZ_PL;        // V^T fp16 [B][E][S]
constexpr size_t OFF_SCB = OFF_VT + SZ_PL;        // scores f32, one batch, 16 MiB
constexpr size_t OFF_PB  = OFF_SCB + 16 * MB;     // P fp16, two batches, 16 MiB
constexpr size_t WS_NEED = OFF_PB + 16 * MB;      // ~164.03 MiB
constexpr size_t OFF_AOQ = OFF_SCB;               // int8 attn_out (16 MiB overlay)

// ---- helpers ---------------------------------------------------------------
typedef const __attribute__((address_space(1))) void* gptr1;
typedef __attribute__((address_space(3))) void* lptr3;

DEVI void gload16(const void* g, void* l) {
  __builtin_amdgcn_global_load_lds((gptr1)g, (lptr3)l, 16, 0, 0);
}

DEVI f32x4 MF16(half8 a, half8 b, f32x4 c) {
  return __builtin_amdgcn_mfma_f32_16x16x32_f16(a, b, c, 0, 0, 0);
}
DEVI i32x4 MFI8(i32x4 a, i32x4 b, i32x4 c) {
  return __builtin_amdgcn_mfma_i32_16x16x64_i8(a, b, c, 0, 0, 0);
}

DEVI float scale_of(const unsigned int* amaxU, int idx) {
  return fmaxf(__uint_as_float(amaxU[idx]) / 127.f, 1e-8f);
}

DEVI signed char q8(float x, float s) {  // true division: bit-exact vs reference
  return (signed char)(int)fminf(fmaxf(rintf(x / s), -127.f), 127.f);
}

// ---- small kernels ---------------------------------------------------------
__global__ void k_zero(float* o, long n) {
  long i = ((long)blockIdx.x * blockDim.x + threadIdx.x) * 4;
  const long stride = (long)gridDim.x * blockDim.x * 4;
  for (; i < n; i += stride) {
    float4 z = {0.f, 0.f, 0.f, 0.f};
    *(float4*)(o + i) = z;
  }
}

__global__ void k_init(unsigned int* a) {
  if (threadIdx.x < 8) a[threadIdx.x] = 0u;
}

__global__ void k_amax(const float* __restrict__ x, long n, unsigned int* amaxU, int idx) {
  long i = ((long)blockIdx.x * blockDim.x + threadIdx.x) * 4;
  const long stride = (long)gridDim.x * blockDim.x * 4;
  float m = 0.f;
  for (; i < n; i += stride) {
    float4 v = *(const float4*)(x + i);
    m = fmaxf(m, fmaxf(fmaxf(fabsf(v.x), fabsf(v.y)), fmaxf(fabsf(v.z), fabsf(v.w))));
  }
#pragma unroll
  for (int o = 32; o; o >>= 1) m = fmaxf(m, __shfl_xor(m, o));
  if ((threadIdx.x & 63) == 0) atomicMax(amaxU + idx, __float_as_uint(m));
}

__global__ void k_quant8(const float* __restrict__ x, signed char* __restrict__ q, long n,
                         const unsigned int* __restrict__ amaxU, int idx) {
  const float s = scale_of(amaxU, idx);
  long i = ((long)blockIdx.x * blockDim.x + threadIdx.x) * 8;
  const long stride = (long)gridDim.x * blockDim.x * 8;
  for (; i < n; i += stride) {
    float4 a = *(const float4*)(x + i);
    float4 b = *(const float4*)(x + i + 4);
    s8x8 o;
    o[0] = q8(a.x, s); o[1] = q8(a.y, s); o[2] = q8(a.z, s); o[3] = q8(a.w, s);
    o[4] = q8(b.x, s); o[5] = q8(b.y, s); o[6] = q8(b.z, s); o[7] = q8(b.w, s);
    *(s8x8*)(q + i) = o;
  }
}

// attn_out fp16 -> int8 (scale from f32 amax gathered in k_pv)
__global__ void k_quant8_f16(char* __restrict__ ws) {
  const unsigned int* amaxU = (const unsigned int*)(ws + OFF_SC);
  const float s = scale_of(amaxU, 7);
  const f16* x = (const f16*)(ws + OFF_VH);
  signed char* o = (signed char*)(ws + OFF_AOQ);
  const long n = NROW * E_;
  long i = ((long)blockIdx.x * blockDim.x + threadIdx.x) * 8;
  const long stride = (long)gridDim.x * blockDim.x * 8;
  for (; i < n; i += stride) {
    half8 v = *(const half8*)(x + i);
    s8x8 w;
#pragma unroll
    for (int j = 0; j < 8; ++j) w[j] = q8((float)v[j], s);
    *(s8x8*)(o + i) = w;
  }
}

// ---- i8 GEMM core: C(128x128) = A(128xK)i8 @ B(128xK)i8^T, BK=128 ----------
DEVI void gemm_core_i8(const signed char* __restrict__ A, const signed char* __restrict__ Bm,
                       int lda, int K, signed char* ldsA, signed char* ldsB,
                       i32x4 acc[4][4], int tid) {
  const int lane = tid & 63, wid = tid >> 6;
  const int wm = wid >> 1, wn = wid & 1;
  const int frow = lane & 15;
  const int fko = (lane >> 4) * 16;  // 16 contiguous K-bytes per lane group
  for (int k0 = 0; k0 < K; k0 += 128) {
    __syncthreads();
#pragma unroll
    for (int it = 0; it < 4; ++it) {  // 1024 chunks of 16B per 16KB tile
      int c = it * 256 + tid;
      int row = c >> 3, cc = c & 7;
      int lb = (it * 256 + (tid & 192)) * 16;  // wave-uniform LDS byte base
      gload16(A + (long)row * lda + k0 + cc * 16, ldsA + lb);
      gload16(Bm + (long)row * lda + k0 + cc * 16, ldsB + lb);
    }
    __syncthreads();
#pragma unroll
    for (int kc = 0; kc < 2; ++kc) {
      i32x4 a[4], b[4];
#pragma unroll
      for (int m = 0; m < 4; ++m)
        a[m] = *(const i32x4*)(ldsA + (wm * 64 + m * 16 + frow) * 128 + kc * 64 + fko);
#pragma unroll
      for (int n = 0; n < 4; ++n)
        b[n] = *(const i32x4*)(ldsB + (wn * 64 + n * 16 + frow) * 128 + kc * 64 + fko);
#pragma unroll
      for (int m = 0; m < 4; ++m)
#pragma unroll
        for (int n = 0; n < 4; ++n)
          acc[m][n] = MFI8(a[m], b[n], acc[m][n]);
    }
  }
}

// ---- fp16 GEMM core: C(128x128) = A(128xK) @ B(128xK)^T, BK=64 -------------
DEVI void gemm_core_f16(const unsigned short* __restrict__ A,
                        const unsigned short* __restrict__ Bm, int lda, int K,
                        unsigned short* ldsA, unsigned short* ldsB, f32x4 acc[4][4], int tid) {
  const int lane = tid & 63, wid = tid >> 6;
  const int wm = wid >> 1, wn = wid & 1;
  const int frow = lane & 15;
  const int fko = (lane >> 4) * 8;
  for (int k0 = 0; k0 < K; k0 += 64) {
    __syncthreads();
#pragma unroll
    for (int it = 0; it < 4; ++it) {
      int c = it * 256 + tid;
      int row = c >> 3, cc = c & 7;
      int lb = (it * 256 + (tid & 192)) * 8;  // elements
      gload16(A + (long)row * lda + k0 + cc * 8, ldsA + lb);
      gload16(Bm + (long)row * lda + k0 + cc * 8, ldsB + lb);
    }
    __syncthreads();
#pragma unroll
    for (int kc = 0; kc < 2; ++kc) {
      half8 a[4], b[4];
#pragma unroll
      for (int m = 0; m < 4; ++m)
        a[m] = *(const half8*)(ldsA + (wm * 64 + m * 16 + frow) * 64 + kc * 32 + fko);
#pragma unroll
      for (int n = 0; n < 4; ++n)
        b[n] = *(const half8*)(ldsB + (wn * 64 + n * 16 + frow) * 64 + kc * 32 + fko);
#pragma unroll
      for (int m = 0; m < 4; ++m)
#pragma unroll
        for (int n = 0; n < 4; ++n)
          acc[m][n] = MF16(a[m], b[n], acc[m][n]);
    }
  }
}

// ---- projections: exact i8 GEMM -> fp16 planes -----------------------------
__global__ __launch_bounds__(256, 2) void k_proj_i8(char* __restrict__ ws,
                                                    const signed char* __restrict__ qi,
                                                    const float* __restrict__ bq,
                                                    const float* __restrict__ bk,
                                                    const float* __restrict__ bv) {
  __shared__ __attribute__((aligned(16))) signed char lA[128 * 128], lB[128 * 128];
  const int tid = threadIdx.x;
  const int z = blockIdx.z;
  const unsigned int* amaxU = (const unsigned int*)(ws + OFF_SC);
  const signed char* A = qi + (size_t)z * NROW * E_ + (size_t)blockIdx.y * 128 * E_;
  const signed char* Bm =
      (const signed char*)(ws + OFF_W + (size_t)z * SZ_WPL) + (size_t)blockIdx.x * 128 * E_;
  f16* H = (f16*)(ws + OFF_QH + (size_t)z * SZ_PL);
  const float* bias = (z == 0) ? bq : ((z == 1) ? bk : bv);
  const float sc = scale_of(amaxU, z) * scale_of(amaxU, 3 + z);
  i32x4 acc[4][4] = {};
  gemm_core_i8(A, Bm, E_, E_, lA, lB, acc, tid);
  const int lane = tid & 63, wid = tid >> 6, wm = wid >> 1, wn = wid & 1;
  const long r0 = (long)blockIdx.y * 128 + wm * 64;
  const int c0 = blockIdx.x * 128 + wn * 64;
#pragma unroll
  for (int m = 0; m < 4; ++m)
#pragma unroll
    for (int n = 0; n < 4; ++n) {
      int col = c0 + n * 16 + (lane & 15);
      float bc = bias[col];
#pragma unroll
      for (int r = 0; r < 4; ++r) {
        long row = r0 + m * 16 + (lane >> 4) * 4 + r;
        H[row * E_ + col] = (f16)(sc * (float)acc[m][n][r] + bc);
      }
    }
}

// ---- V transpose: vh [b][s][e] -> vT [b][e][s] -----------------------------
__global__ void k_transpose(char* __restrict__ ws) {
  __shared__ f16 t[64][72];
  const int b = blockIdx.z, e0 = blockIdx.x * 64, s0 = blockIdx.y * 64;
  const f16* V = (const f16*)(ws + OFF_VH) + (size_t)b * S_ * E_;
  f16* VT = (f16*)(ws + OFF_VT) + (size_t)b * E_ * S_;
  const int tid = threadIdx.x;
  const int r = tid >> 2, cc = (tid & 3) * 16;
#pragma unroll
  for (int j = 0; j < 2; ++j) {
    half8 v = *(const half8*)(V + (size_t)(s0 + r) * E_ + e0 + cc + j * 8);
#pragma unroll
    for (int q = 0; q < 8; ++q) t[cc + j * 8 + q][r] = v[q];
  }
  __syncthreads();
#pragma unroll
  for (int j = 0; j < 2; ++j) {
    half8 w;
#pragma unroll
    for (int q = 0; q < 8; ++q) w[q] = t[r][cc + j * 8 + q];
    *(half8*)(VT + (size_t)(e0 + r) * S_ + s0 + cc + j * 8) = w;
  }
}

// ---- scores (one batch): C = 0.125 * qh@kh^T, fp16 MFMA --------------------
__global__ __launch_bounds__(256, 2) void k_scores(char* __restrict__ ws, int b) {
  __shared__ __attribute__((aligned(16))) unsigned short lA[128 * 64], lB[128 * 64];
  const int tid = threadIdx.x;
  const unsigned short* A = (const unsigned short*)(ws + OFF_QH) +
                            ((size_t)b * S_ + (size_t)blockIdx.y * 128) * E_;
  const unsigned short* Bm = (const unsigned short*)(ws + OFF_KH) +
                             ((size_t)b * S_ + (size_t)blockIdx.x * 128) * E_;
  float* C = (float*)(ws + OFF_SCB);
  f32x4 acc[4][4] = {};
  gemm_core_f16(A, Bm, E_, E_, lA, lB, acc, tid);
  const int lane = tid & 63, wid = tid >> 6, wm = wid >> 1, wn = wid & 1;
  const int r0 = blockIdx.y * 128 + wm * 64;
  const int c0 = blockIdx.x * 128 + wn * 64;
#pragma unroll
  for (int m = 0; m < 4; ++m)
#pragma unroll
    for (int n = 0; n < 4; ++n) {
      int col = c0 + n * 16 + (lane & 15);
#pragma unroll
      for (int r = 0; r < 4; ++r) {
        int row = r0 + m * 16 + (lane >> 4) * 4 + r;
        C[(size_t)row * S_ + col] = 0.125f * acc[m][n][r];
      }
    }
}

// ---- row softmax (one batch): scores f32 -> P fp16 (unnorm) + 1/rowsum -----
__global__ __launch_bounds__(256) void k_softmax(char* __restrict__ ws, int pp) {
  const long row = blockIdx.x;
  const float* src = (const float*)(ws + OFF_SCB) + row * S_;
  f16* P = (f16*)(ws + OFF_PB) + (size_t)pp * S_ * S_ + row * S_;
  float* RS = (float*)(ws + OFF_RS) + pp * S_;
  const int tid = threadIdx.x, lane = tid & 63, wid = tid >> 6;
  float4 v0 = ((const float4*)src)[tid];
  float4 v1 = ((const float4*)src)[tid + 256];
  float m = fmaxf(fmaxf(fmaxf(v0.x, v0.y), fmaxf(v0.z, v0.w)),
                  fmaxf(fmaxf(v1.x, v1.y), fmaxf(v1.z, v1.w)));
#pragma unroll
  for (int o = 32; o; o >>= 1) m = fmaxf(m, __shfl_xor(m, o));
  __shared__ float redm[4], reds[4];
  if (lane == 0) redm[wid] = m;
  __syncthreads();
  m = fmaxf(fmaxf(redm[0], redm[1]), fmaxf(redm[2], redm[3]));
  float e0 = expf(v0.x - m), e1 = expf(v0.y - m), e2 = expf(v0.z - m), e3 = expf(v0.w - m);
  float e4 = expf(v1.x - m), e5 = expf(v1.y - m), e6 = expf(v1.z - m), e7 = expf(v1.w - m);
  float s = ((e0 + e1) + (e2 + e3)) + ((e4 + e5) + (e6 + e7));
#pragma unroll
  for (int o = 32; o; o >>= 1) s += __shfl_xor(s, o);
  if (lane == 0) reds[wid] = s;
  __syncthreads();
  s = (reds[0] + reds[1]) + (reds[2] + reds[3]);
  if (tid == 0) RS[row] = 1.f / s;
  half4 p0 = {(f16)e0, (f16)e1, (f16)e2, (f16)e3};
  half4 p1 = {(f16)e4, (f16)e5, (f16)e6, (f16)e7};
  *(half4*)(P + (long)tid * 4) = p0;
  *(half4*)(P + 1024 + (long)tid * 4) = p1;
}

// ---- PV (batch pair): attn_out = (P @ vT^T) * recip -> fp16 + f32 amax -----
__global__ __launch_bounds__(256, 2) void k_pv(char* __restrict__ ws, int bb) {
  __shared__ __attribute__((aligned(16))) unsigned short lA[128 * 64], lB[128 * 64];
  const int tid = threadIdx.x;
  const int z = blockIdx.z;
  const int b = bb + z;
  const unsigned short* A = (const unsigned short*)(ws + OFF_PB) + (size_t)z * S_ * S_ +
                            (size_t)blockIdx.y * 128 * S_;
  const unsigned short* Bm = (const unsigned short*)(ws + OFF_VT) + (size_t)b * E_ * S_ +
                             (size_t)blockIdx.x * 128 * S_;
  f32x4 acc[4][4] = {};
  gemm_core_f16(A, Bm, S_, S_, lA, lB, acc, tid);
  const float* RS = (const float*)(ws + OFF_RS) + z * S_;
  f16* O = (f16*)(ws + OFF_VH) + (size_t)b * S_ * E_;
  unsigned int* amaxU = (unsigned int*)(ws + OFF_SC);
  const int lane = tid & 63, wid = tid >> 6, wm = wid >> 1, wn = wid & 1;
  const int r0 = blockIdx.y * 128 + wm * 64;
  const int c0 = blockIdx.x * 128 + wn * 64;
  float mx = 0.f;
#pragma unroll
  for (int m = 0; m < 4; ++m)
#pragma unroll
    for (int n = 0; n < 4; ++n) {
      int col = c0 + n * 16 + (lane & 15);
#pragma unroll
      for (int r = 0; r < 4; ++r) {
        int row = r0 + m * 16 + (lane >> 4) * 4 + r;
        float o = acc[m][n][r] * RS[row];
        O[(size_t)row * E_ + col] = (f16)o;
        mx = fmaxf(mx, fabsf(o));
      }
    }
#pragma unroll
  for (int o2 = 32; o2; o2 >>= 1) mx = fmaxf(mx, __shfl_xor(mx, o2));
  if (lane == 0) atomicMax(amaxU + 7, __float_as_uint(mx));
}

// ---- final projection: exact i8 GEMM -> d_out f32 --------------------------
__global__ __launch_bounds__(256, 2) void k_final_i8(char* __restrict__ ws,
                                                     const float* __restrict__ bp,
                                                     float* __restrict__ out) {
  __shared__ __attribute__((aligned(16))) signed char lA[128 * 128], lB[128 * 128];
  const int tid = threadIdx.x;
  const unsigned int* amaxU = (const unsigned int*)(ws + OFF_SC);
  const signed char* A = (const signed char*)(ws + OFF_AOQ) + (size_t)blockIdx.y * 128 * E_;
  const signed char* Bm =
      (const signed char*)(ws + OFF_W + 3 * SZ_WPL) + (size_t)blockIdx.x * 128 * E_;
  const float sc = scale_of(amaxU, 7) * scale_of(amaxU, 6);
  i32x4 acc[4][4] = {};
  gemm_core_i8(A, Bm, E_, E_, lA, lB, acc, tid);
  const int lane = tid & 63, wid = tid >> 6, wm = wid >> 1, wn = wid & 1;
  const long r0 = (long)blockIdx.y * 128 + wm * 64;
  const int c0 = blockIdx.x * 128 + wn * 64;
#pragma unroll
  for (int m = 0; m < 4; ++m)
#pragma unroll
    for (int n = 0; n < 4; ++n) {
      int col = c0 + n * 16 + (lane & 15);
      float bc = bp[col];
#pragma unroll
      for (int r = 0; r < 4; ++r) {
        long row = r0 + m * 16 + (lane >> 4) * 4 + r;
        out[row * E_ + col] = sc * (float)acc[m][n][r] + bc;
      }
    }
}

// ---------------------------------------------------------------------------
extern "C" void kernel_launch(void* const* d_in, const int* in_sizes, int n_in,
                              void* d_out, int out_size, void* d_ws, size_t ws_size,
                              hipStream_t stream) {
  (void)in_sizes; (void)n_in; (void)out_size;
  char* ws = (char*)d_ws;
  const float* query = (const float*)d_in[0];
  const float* key   = (const float*)d_in[1];
  const float* value = (const float*)d_in[2];
  const float* Wq = (const float*)d_in[3];
  const float* bq = (const float*)d_in[4];
  const float* Wk = (const float*)d_in[5];
  const float* bk = (const float*)d_in[6];
  const float* Wv = (const float*)d_in[7];
  const float* bv = (const float*)d_in[8];
  const float* Wp = (const float*)d_in[9];
  const float* bp = (const float*)d_in[10];

  const long nIn = NROW * E_;  // 16,777,216
  const long nW = (long)E_ * E_;

  if (ws_size < WS_NEED) {  // diagnostic fallback: zeros, no OOB writes
    k_zero<<<dim3(2048), dim3(256), 0, stream>>>((float*)d_out, nIn);
    return;
  }

  unsigned int* amaxU = (unsigned int*)(ws + OFF_SC);
  // d_out (64 MiB) doubles as int8 input-plane scratch until k_final_i8
  signed char* qi = (signed char*)d_out;

  k_init<<<dim3(1), dim3(64), 0, stream>>>(amaxU);

  k_amax<<<dim3(1024), dim3(256), 0, stream>>>(query, nIn, amaxU, 0);
  k_amax<<<dim3(1024), dim3(256), 0, stream>>>(key,   nIn, amaxU, 1);
  k_amax<<<dim3(1024), dim3(256), 0, stream>>>(value, nIn, amaxU, 2);
  k_amax<<<dim3(256),  dim3(256), 0, stream>>>(Wq, nW, amaxU, 3);
  k_amax<<<dim3(256),  dim3(256), 0, stream>>>(Wk, nW, amaxU, 4);
  k_amax<<<dim3(256),  dim3(256), 0, stream>>>(Wv, nW, amaxU, 5);
  k_amax<<<dim3(256),  dim3(256), 0, stream>>>(Wp, nW, amaxU, 6);

  k_quant8<<<dim3(1024), dim3(256), 0, stream>>>(query, qi,                 nIn, amaxU, 0);
  k_quant8<<<dim3(1024), dim3(256), 0, stream>>>(key,   qi + (size_t)nIn,   nIn, amaxU, 1);
  k_quant8<<<dim3(1024), dim3(256), 0, stream>>>(value, qi + 2 * (size_t)nIn, nIn, amaxU, 2);
  k_quant8<<<dim3(128), dim3(256), 0, stream>>>(Wq, (signed char*)(ws + OFF_W),              nW, amaxU, 3);
  k_quant8<<<dim3(128), dim3(256), 0, stream>>>(Wk, (signed char*)(ws + OFF_W + SZ_WPL),     nW, amaxU, 4);
  k_quant8<<<dim3(128), dim3(256), 0, stream>>>(Wv, (signed char*)(ws + OFF_W + 2 * SZ_WPL), nW, amaxU, 5);
  k_quant8<<<dim3(128), dim3(256), 0, stream>>>(Wp, (signed char*)(ws + OFF_W + 3 * SZ_WPL), nW, amaxU, 6);

  k_proj_i8<<<dim3(8, 128, 3), dim3(256), 0, stream>>>(ws, qi, bq, bk, bv);
  k_transpose<<<dim3(16, 32, 8), dim3(256), 0, stream>>>(ws);

  for (int bb = 0; bb < B_; bb += 2) {
    k_scores<<<dim3(16, 16), dim3(256), 0, stream>>>(ws, bb);
    k_softmax<<<dim3(2048), dim3(256), 0, stream>>>(ws, 0);
    k_scores<<<dim3(16, 16), dim3(256), 0, stream>>>(ws, bb + 1);
    k_softmax<<<dim3(2048), dim3(256), 0, stream>>>(ws, 1);
    k_pv<<<dim3(8, 16, 2), dim3(256), 0, stream>>>(ws, bb);
  }

  k_quant8_f16<<<dim3(1024), dim3(256), 0, stream>>>(ws);
  k_final_i8<<<dim3(8, 128), dim3(256), 0, stream>>>(ws, bp, (float*)d_out);
}

// Round 4
// 656.025 us; speedup vs baseline: 1.9083x; 1.3566x over previous
//
#include <hip/hip_runtime.h>

// ---------------------------------------------------------------------------
// QuantizedAttention (B=8, S=2048, E=1024), no head split: scores are [B,S,S].
//   fused amax (inputs z=3 / weights z=4) -> int8 quant (true div, bit-exact)
//   k_proj_i8: exact i8 MFMA GEMM (i32 acc) -> q,k,v fp16 planes  [T1 swizzle]
//   k_transpose: v -> vT [B][E][S] fp16
//   per 4-batch group:
//     k_scores z=4: 0.125 * qh@kh^T -> f32 scores (4 batches)     [T1 swizzle]
//     k_softmax: row softmax f32, P fp16 written IN-PLACE over scores + 1/sum
//     k_pv z=4: (P @ vT^T) * recip -> attn_out fp16 + f32 amax    [T1 swizzle]
//   quant attn_out -> int8 -> exact i8 MFMA final proj -> d_out   [T1 swizzle]
// Peak workspace ~196 MiB (proven envelope >= 200 MiB).
// ---------------------------------------------------------------------------

typedef __attribute__((ext_vector_type(4))) float f32x4;
typedef __attribute__((ext_vector_type(4))) int i32x4;
typedef __attribute__((ext_vector_type(8))) char s8x8;
typedef _Float16 f16;
typedef _Float16 half8 __attribute__((ext_vector_type(8)));
typedef _Float16 half4 __attribute__((ext_vector_type(4)));

#define DEVI static __device__ __forceinline__

constexpr int B_ = 8, S_ = 2048, E_ = 1024;
constexpr long NROW = (long)B_ * S_;  // 16384

constexpr size_t KB = 1024, MB = 1024 * 1024;
constexpr size_t OFF_SC  = 0;                     // u32[8] amax bits
constexpr size_t OFF_RS  = 1 * KB;                // 8192 f32 recip rowsums (4 batches)
constexpr size_t OFF_W   = 64 * KB;               // 4 weight planes int8, 1 MiB each
constexpr size_t SZ_WPL  = (size_t)E_ * E_;       // 1 MiB
constexpr size_t SZ_PL   = (size_t)NROW * E_ * 2; // 32 MiB (fp16 plane)
constexpr size_t OFF_QH  = OFF_W + 4 * SZ_WPL;
constexpr size_t OFF_KH  = OFF_QH + SZ_PL;
constexpr size_t OFF_VH  = OFF_KH + SZ_PL;        // later overlay: attn_out fp16
constexpr size_t OFF_VT  = OFF_VH + SZ_PL;        // V^T fp16 [B][E][S]
constexpr size_t OFF_SCB = OFF_VT + SZ_PL;        // scores f32, 4 batches, 64 MiB
constexpr size_t WS_NEED = OFF_SCB + 64 * MB;     // ~196.06 MiB
constexpr size_t OFF_AOQ = OFF_SCB;               // int8 attn_out (16 MiB overlay)

// ---- helpers ---------------------------------------------------------------
typedef const __attribute__((address_space(1))) void* gptr1;
typedef __attribute__((address_space(3))) void* lptr3;

DEVI void gload16(const void* g, void* l) {
  __builtin_amdgcn_global_load_lds((gptr1)g, (lptr3)l, 16, 0, 0);
}

DEVI f32x4 MF16(half8 a, half8 b, f32x4 c) {
  return __builtin_amdgcn_mfma_f32_16x16x32_f16(a, b, c, 0, 0, 0);
}
DEVI i32x4 MFI8(i32x4 a, i32x4 b, i32x4 c) {
  return __builtin_amdgcn_mfma_i32_16x16x64_i8(a, b, c, 0, 0, 0);
}

DEVI float scale_of(const unsigned int* amaxU, int idx) {
  return fmaxf(__uint_as_float(amaxU[idx]) / 127.f, 1e-8f);
}

DEVI signed char q8(float x, float s) {  // true division: bit-exact vs reference
  return (signed char)(int)fminf(fmaxf(rintf(x / s), -127.f), 127.f);
}

// T1 XCD-chunked swizzle: hardware id d (round-robin over 8 XCDs) -> work id w
// such that each XCD owns a contiguous chunk of work ids. n must be %8==0.
DEVI int xcd_swz(int d, int n) { return (d & 7) * (n >> 3) + (d >> 3); }

// ---- small kernels ---------------------------------------------------------
__global__ void k_zero(float* o, long n) {
  long i = ((long)blockIdx.x * blockDim.x + threadIdx.x) * 4;
  const long stride = (long)gridDim.x * blockDim.x * 4;
  for (; i < n; i += stride) {
    float4 z = {0.f, 0.f, 0.f, 0.f};
    *(float4*)(o + i) = z;
  }
}

__global__ void k_init(unsigned int* a) {
  if (threadIdx.x < 8) a[threadIdx.x] = 0u;
}

DEVI void amax_body(const float* __restrict__ x, long n, unsigned int* amaxU, int idx) {
  long i = ((long)blockIdx.x * blockDim.x + threadIdx.x) * 8;
  const long stride = (long)gridDim.x * blockDim.x * 8;
  float m = 0.f;
  for (; i < n; i += stride) {
    float4 a = *(const float4*)(x + i);
    float4 b = *(const float4*)(x + i + 4);
    m = fmaxf(m, fmaxf(fmaxf(fabsf(a.x), fabsf(a.y)), fmaxf(fabsf(a.z), fabsf(a.w))));
    m = fmaxf(m, fmaxf(fmaxf(fabsf(b.x), fabsf(b.y)), fmaxf(fabsf(b.z), fabsf(b.w))));
  }
#pragma unroll
  for (int o = 32; o; o >>= 1) m = fmaxf(m, __shfl_xor(m, o));
  if ((threadIdx.x & 63) == 0) atomicMax(amaxU + idx, __float_as_uint(m));
}

__global__ void k_amax_in(const float* __restrict__ q, const float* __restrict__ k,
                          const float* __restrict__ v, long n, unsigned int* amaxU) {
  const int z = blockIdx.z;
  amax_body(z == 0 ? q : (z == 1 ? k : v), n, amaxU, z);
}
__global__ void k_amax_w(const float* __restrict__ a, const float* __restrict__ b,
                         const float* __restrict__ c, const float* __restrict__ d,
                         long n, unsigned int* amaxU) {
  const int z = blockIdx.z;
  amax_body(z == 0 ? a : (z == 1 ? b : (z == 2 ? c : d)), n, amaxU, 3 + z);
}

DEVI void quant8_body(const float* __restrict__ x, signed char* __restrict__ q, long n,
                      float s) {
  long i = ((long)blockIdx.x * blockDim.x + threadIdx.x) * 8;
  const long stride = (long)gridDim.x * blockDim.x * 8;
  for (; i < n; i += stride) {
    float4 a = *(const float4*)(x + i);
    float4 b = *(const float4*)(x + i + 4);
    s8x8 o;
    o[0] = q8(a.x, s); o[1] = q8(a.y, s); o[2] = q8(a.z, s); o[3] = q8(a.w, s);
    o[4] = q8(b.x, s); o[5] = q8(b.y, s); o[6] = q8(b.z, s); o[7] = q8(b.w, s);
    *(s8x8*)(q + i) = o;
  }
}

__global__ void k_quant_in(const float* __restrict__ q, const float* __restrict__ k,
                           const float* __restrict__ v, signed char* __restrict__ out,
                           long n, const unsigned int* __restrict__ amaxU) {
  const int z = blockIdx.z;
  quant8_body(z == 0 ? q : (z == 1 ? k : v), out + (size_t)z * n, n, scale_of(amaxU, z));
}
__global__ void k_quant_w(const float* __restrict__ a, const float* __restrict__ b,
                          const float* __restrict__ c, const float* __restrict__ d,
                          signed char* __restrict__ out, long n,
                          const unsigned int* __restrict__ amaxU) {
  const int z = blockIdx.z;
  quant8_body(z == 0 ? a : (z == 1 ? b : (z == 2 ? c : d)), out + (size_t)z * n, n,
              scale_of(amaxU, 3 + z));
}

// attn_out fp16 -> int8
__global__ void k_quant8_f16(char* __restrict__ ws) {
  const unsigned int* amaxU = (const unsigned int*)(ws + OFF_SC);
  const float s = scale_of(amaxU, 7);
  const f16* x = (const f16*)(ws + OFF_VH);
  signed char* o = (signed char*)(ws + OFF_AOQ);
  const long n = NROW * E_;
  long i = ((long)blockIdx.x * blockDim.x + threadIdx.x) * 8;
  const long stride = (long)gridDim.x * blockDim.x * 8;
  for (; i < n; i += stride) {
    half8 v = *(const half8*)(x + i);
    s8x8 w;
#pragma unroll
    for (int j = 0; j < 8; ++j) w[j] = q8((float)v[j], s);
    *(s8x8*)(o + i) = w;
  }
}

// ---- i8 GEMM core: C(128x128) = A(128xK)i8 @ B(128xK)i8^T, BK=128 ----------
DEVI void gemm_core_i8(const signed char* __restrict__ A, const signed char* __restrict__ Bm,
                       int lda, int K, signed char* ldsA, signed char* ldsB,
                       i32x4 acc[4][4], int tid) {
  const int lane = tid & 63, wid = tid >> 6;
  const int wm = wid >> 1, wn = wid & 1;
  const int frow = lane & 15;
  const int fko = (lane >> 4) * 16;
  for (int k0 = 0; k0 < K; k0 += 128) {
    __syncthreads();
#pragma unroll
    for (int it = 0; it < 4; ++it) {
      int c = it * 256 + tid;
      int row = c >> 3, cc = c & 7;
      int lb = (it * 256 + (tid & 192)) * 16;
      gload16(A + (long)row * lda + k0 + cc * 16, ldsA + lb);
      gload16(Bm + (long)row * lda + k0 + cc * 16, ldsB + lb);
    }
    __syncthreads();
#pragma unroll
    for (int kc = 0; kc < 2; ++kc) {
      i32x4 a[4], b[4];
#pragma unroll
      for (int m = 0; m < 4; ++m)
        a[m] = *(const i32x4*)(ldsA + (wm * 64 + m * 16 + frow) * 128 + kc * 64 + fko);
#pragma unroll
      for (int n = 0; n < 4; ++n)
        b[n] = *(const i32x4*)(ldsB + (wn * 64 + n * 16 + frow) * 128 + kc * 64 + fko);
#pragma unroll
      for (int m = 0; m < 4; ++m)
#pragma unroll
        for (int n = 0; n < 4; ++n)
          acc[m][n] = MFI8(a[m], b[n], acc[m][n]);
    }
  }
}

// ---- fp16 GEMM core: C(128x128) = A(128xK) @ B(128xK)^T, BK=64 -------------
DEVI void gemm_core_f16(const unsigned short* __restrict__ A,
                        const unsigned short* __restrict__ Bm, int lda, int ldb, int K,
                        unsigned short* ldsA, unsigned short* ldsB, f32x4 acc[4][4], int tid) {
  const int lane = tid & 63, wid = tid >> 6;
  const int wm = wid >> 1, wn = wid & 1;
  const int frow = lane & 15;
  const int fko = (lane >> 4) * 8;
  for (int k0 = 0; k0 < K; k0 += 64) {
    __syncthreads();
#pragma unroll
    for (int it = 0; it < 4; ++it) {
      int c = it * 256 + tid;
      int row = c >> 3, cc = c & 7;
      int lb = (it * 256 + (tid & 192)) * 8;
      gload16(A + (long)row * lda + k0 + cc * 8, ldsA + lb);
      gload16(Bm + (long)row * ldb + k0 + cc * 8, ldsB + lb);
    }
    __syncthreads();
#pragma unroll
    for (int kc = 0; kc < 2; ++kc) {
      half8 a[4], b[4];
#pragma unroll
      for (int m = 0; m < 4; ++m)
        a[m] = *(const half8*)(ldsA + (wm * 64 + m * 16 + frow) * 64 + kc * 32 + fko);
#pragma unroll
      for (int n = 0; n < 4; ++n)
        b[n] = *(const half8*)(ldsB + (wn * 64 + n * 16 + frow) * 64 + kc * 32 + fko);
#pragma unroll
      for (int m = 0; m < 4; ++m)
#pragma unroll
        for (int n = 0; n < 4; ++n)
          acc[m][n] = MF16(a[m], b[n], acc[m][n]);
    }
  }
}

// ---- projections: exact i8 GEMM -> fp16 planes -----------------------------
__global__ __launch_bounds__(256, 2) void k_proj_i8(char* __restrict__ ws,
                                                    const signed char* __restrict__ qi,
                                                    const float* __restrict__ bq,
                                                    const float* __restrict__ bk,
                                                    const float* __restrict__ bv) {
  __shared__ __attribute__((aligned(16))) signed char lA[128 * 128], lB[128 * 128];
  const int tid = threadIdx.x;
  int d = blockIdx.x + 8 * blockIdx.y + 1024 * blockIdx.z;
  int w = xcd_swz(d, 3072);
  const int bx = w & 7, by = (w >> 3) & 127, z = w >> 10;
  const unsigned int* amaxU = (const unsigned int*)(ws + OFF_SC);
  const signed char* A = qi + (size_t)z * NROW * E_ + (size_t)by * 128 * E_;
  const signed char* Bm =
      (const signed char*)(ws + OFF_W + (size_t)z * SZ_WPL) + (size_t)bx * 128 * E_;
  f16* H = (f16*)(ws + OFF_QH + (size_t)z * SZ_PL);
  const float* bias = (z == 0) ? bq : ((z == 1) ? bk : bv);
  const float sc = scale_of(amaxU, z) * scale_of(amaxU, 3 + z);
  i32x4 acc[4][4] = {};
  gemm_core_i8(A, Bm, E_, E_, lA, lB, acc, tid);
  const int lane = tid & 63, wid = tid >> 6, wm = wid >> 1, wn = wid & 1;
  const long r0 = (long)by * 128 + wm * 64;
  const int c0 = bx * 128 + wn * 64;
#pragma unroll
  for (int m = 0; m < 4; ++m)
#pragma unroll
    for (int n = 0; n < 4; ++n) {
      int col = c0 + n * 16 + (lane & 15);
      float bc = bias[col];
#pragma unroll
      for (int r = 0; r < 4; ++r) {
        long row = r0 + m * 16 + (lane >> 4) * 4 + r;
        H[row * E_ + col] = (f16)(sc * (float)acc[m][n][r] + bc);
      }
    }
}

// ---- V transpose: vh [b][s][e] -> vT [b][e][s] -----------------------------
__global__ void k_transpose(char* __restrict__ ws) {
  __shared__ f16 t[64][72];
  const int b = blockIdx.z, e0 = blockIdx.x * 64, s0 = blockIdx.y * 64;
  const f16* V = (const f16*)(ws + OFF_VH) + (size_t)b * S_ * E_;
  f16* VT = (f16*)(ws + OFF_VT) + (size_t)b * E_ * S_;
  const int tid = threadIdx.x;
  const int r = tid >> 2, cc = (tid & 3) * 16;
#pragma unroll
  for (int j = 0; j < 2; ++j) {
    half8 v = *(const half8*)(V + (size_t)(s0 + r) * E_ + e0 + cc + j * 8);
#pragma unroll
    for (int q = 0; q < 8; ++q) t[cc + j * 8 + q][r] = v[q];
  }
  __syncthreads();
#pragma unroll
  for (int j = 0; j < 2; ++j) {
    half8 w;
#pragma unroll
    for (int q = 0; q < 8; ++q) w[q] = t[r][cc + j * 8 + q];
    *(half8*)(VT + (size_t)(e0 + r) * S_ + s0 + cc + j * 8) = w;
  }
}

// ---- scores (4-batch group): C = 0.125 * qh@kh^T, fp16 MFMA ----------------
__global__ __launch_bounds__(256, 2) void k_scores(char* __restrict__ ws, int b0) {
  __shared__ __attribute__((aligned(16))) unsigned short lA[128 * 64], lB[128 * 64];
  const int tid = threadIdx.x;
  int d = blockIdx.x + 16 * blockIdx.y + 256 * blockIdx.z;
  int w = xcd_swz(d, 1024);
  const int bx = w & 15, by = (w >> 4) & 15, zb = w >> 8;
  const int b = b0 + zb;
  const unsigned short* A =
      (const unsigned short*)(ws + OFF_QH) + ((size_t)b * S_ + (size_t)by * 128) * E_;
  const unsigned short* Bm =
      (const unsigned short*)(ws + OFF_KH) + ((size_t)b * S_ + (size_t)bx * 128) * E_;
  float* C = (float*)(ws + OFF_SCB) + (size_t)zb * S_ * S_;
  f32x4 acc[4][4] = {};
  gemm_core_f16(A, Bm, E_, E_, E_, lA, lB, acc, tid);
  const int lane = tid & 63, wid = tid >> 6, wm = wid >> 1, wn = wid & 1;
  const int r0 = by * 128 + wm * 64;
  const int c0 = bx * 128 + wn * 64;
#pragma unroll
  for (int m = 0; m < 4; ++m)
#pragma unroll
    for (int n = 0; n < 4; ++n) {
      int col = c0 + n * 16 + (lane & 15);
#pragma unroll
      for (int r = 0; r < 4; ++r) {
        int row = r0 + m * 16 + (lane >> 4) * 4 + r;
        C[(size_t)row * S_ + col] = 0.125f * acc[m][n][r];
      }
    }
}

// ---- row softmax (4-batch group), P fp16 written IN-PLACE over scores ------
// Safe: every thread's loads complete before the first __syncthreads (data
// dependency through the max reduce); all P stores happen after it.
__global__ __launch_bounds__(256) void k_softmax(char* __restrict__ ws) {
  const long row = blockIdx.x;  // 0..8191 (4 batches)
  float* src = (float*)(ws + OFF_SCB) + row * S_;
  f16* P = (f16*)src;
  float* RS = (float*)(ws + OFF_RS);
  const int tid = threadIdx.x, lane = tid & 63, wid = tid >> 6;
  float4 v0 = ((const float4*)src)[tid];
  float4 v1 = ((const float4*)src)[tid + 256];
  float m = fmaxf(fmaxf(fmaxf(v0.x, v0.y), fmaxf(v0.z, v0.w)),
                  fmaxf(fmaxf(v1.x, v1.y), fmaxf(v1.z, v1.w)));
#pragma unroll
  for (int o = 32; o; o >>= 1) m = fmaxf(m, __shfl_xor(m, o));
  __shared__ float redm[4], reds[4];
  if (lane == 0) redm[wid] = m;
  __syncthreads();
  m = fmaxf(fmaxf(redm[0], redm[1]), fmaxf(redm[2], redm[3]));
  float e0 = expf(v0.x - m), e1 = expf(v0.y - m), e2 = expf(v0.z - m), e3 = expf(v0.w - m);
  float e4 = expf(v1.x - m), e5 = expf(v1.y - m), e6 = expf(v1.z - m), e7 = expf(v1.w - m);
  float s = ((e0 + e1) + (e2 + e3)) + ((e4 + e5) + (e6 + e7));
#pragma unroll
  for (int o = 32; o; o >>= 1) s += __shfl_xor(s, o);
  if (lane == 0) reds[wid] = s;
  __syncthreads();
  s = (reds[0] + reds[1]) + (reds[2] + reds[3]);
  if (tid == 0) RS[row] = 1.f / s;
  half4 p0 = {(f16)e0, (f16)e1, (f16)e2, (f16)e3};
  half4 p1 = {(f16)e4, (f16)e5, (f16)e6, (f16)e7};
  *(half4*)(P + (long)tid * 4) = p0;
  *(half4*)(P + 1024 + (long)tid * 4) = p1;
}

// ---- PV (4-batch group): attn_out = (P @ vT^T) * recip -> fp16 + f32 amax --
__global__ __launch_bounds__(256, 2) void k_pv(char* __restrict__ ws, int b0) {
  __shared__ __attribute__((aligned(16))) unsigned short lA[128 * 64], lB[128 * 64];
  const int tid = threadIdx.x;
  int d = blockIdx.x + 8 * blockIdx.y + 128 * blockIdx.z;
  int w = xcd_swz(d, 512);
  const int bx = w & 7, by = (w >> 3) & 15, zb = w >> 7;
  const int b = b0 + zb;
  // P in-place over scores: fp16 data at row pitch 2*S_ elements
  const unsigned short* A = (const unsigned short*)((float*)(ws + OFF_SCB) +
                                                    (size_t)zb * S_ * S_) +
                            (size_t)by * 128 * (2 * S_);
  const unsigned short* Bm = (const unsigned short*)(ws + OFF_VT) + (size_t)b * E_ * S_ +
                             (size_t)bx * 128 * S_;
  f32x4 acc[4][4] = {};
  gemm_core_f16(A, Bm, 2 * S_, S_, S_, lA, lB, acc, tid);
  const float* RS = (const float*)(ws + OFF_RS) + (size_t)zb * S_;
  f16* O = (f16*)(ws + OFF_VH) + (size_t)b * S_ * E_;
  unsigned int* amaxU = (unsigned int*)(ws + OFF_SC);
  const int lane = tid & 63, wid = tid >> 6, wm = wid >> 1, wn = wid & 1;
  const int r0 = by * 128 + wm * 64;
  const int c0 = bx * 128 + wn * 64;
  float mx = 0.f;
#pragma unroll
  for (int m = 0; m < 4; ++m)
#pragma unroll
    for (int n = 0; n < 4; ++n) {
      int col = c0 + n * 16 + (lane & 15);
#pragma unroll
      for (int r = 0; r < 4; ++r) {
        int row = r0 + m * 16 + (lane >> 4) * 4 + r;
        float o = acc[m][n][r] * RS[row];
        O[(size_t)row * E_ + col] = (f16)o;
        mx = fmaxf(mx, fabsf(o));
      }
    }
#pragma unroll
  for (int o2 = 32; o2; o2 >>= 1) mx = fmaxf(mx, __shfl_xor(mx, o2));
  if (lane == 0) atomicMax(amaxU + 7, __float_as_uint(mx));
}

// ---- final projection: exact i8 GEMM -> d_out f32 --------------------------
__global__ __launch_bounds__(256, 2) void k_final_i8(char* __restrict__ ws,
                                                     const float* __restrict__ bp,
                                                     float* __restrict__ out) {
  __shared__ __attribute__((aligned(16))) signed char lA[128 * 128], lB[128 * 128];
  const int tid = threadIdx.x;
  int d = blockIdx.x + 8 * blockIdx.y;
  int w = xcd_swz(d, 1024);
  const int bx = w & 7, by = w >> 3;
  const unsigned int* amaxU = (const unsigned int*)(ws + OFF_SC);
  const signed char* A = (const signed char*)(ws + OFF_AOQ) + (size_t)by * 128 * E_;
  const signed char* Bm =
      (const signed char*)(ws + OFF_W + 3 * SZ_WPL) + (size_t)bx * 128 * E_;
  const float sc = scale_of(amaxU, 7) * scale_of(amaxU, 6);
  i32x4 acc[4][4] = {};
  gemm_core_i8(A, Bm, E_, E_, lA, lB, acc, tid);
  const int lane = tid & 63, wid = tid >> 6, wm = wid >> 1, wn = wid & 1;
  const long r0 = (long)by * 128 + wm * 64;
  const int c0 = bx * 128 + wn * 64;
#pragma unroll
  for (int m = 0; m < 4; ++m)
#pragma unroll
    for (int n = 0; n < 4; ++n) {
      int col = c0 + n * 16 + (lane & 15);
      float bc = bp[col];
#pragma unroll
      for (int r = 0; r < 4; ++r) {
        long row = r0 + m * 16 + (lane >> 4) * 4 + r;
        out[row * E_ + col] = sc * (float)acc[m][n][r] + bc;
      }
    }
}

// ---------------------------------------------------------------------------
extern "C" void kernel_launch(void* const* d_in, const int* in_sizes, int n_in,
                              void* d_out, int out_size, void* d_ws, size_t ws_size,
                              hipStream_t stream) {
  (void)in_sizes; (void)n_in; (void)out_size;
  char* ws = (char*)d_ws;
  const float* query = (const float*)d_in[0];
  const float* key   = (const float*)d_in[1];
  const float* value = (const float*)d_in[2];
  const float* Wq = (const float*)d_in[3];
  const float* bq = (const float*)d_in[4];
  const float* Wk = (const float*)d_in[5];
  const float* bk = (const float*)d_in[6];
  const float* Wv = (const float*)d_in[7];
  const float* bv = (const float*)d_in[8];
  const float* Wp = (const float*)d_in[9];
  const float* bp = (const float*)d_in[10];

  const long nIn = NROW * E_;  // 16,777,216
  const long nW = (long)E_ * E_;

  if (ws_size < WS_NEED) {  // diagnostic fallback: zeros, no OOB writes
    k_zero<<<dim3(2048), dim3(256), 0, stream>>>((float*)d_out, nIn);
    return;
  }

  unsigned int* amaxU = (unsigned int*)(ws + OFF_SC);
  signed char* qi = (signed char*)d_out;  // int8 q/k/v planes live in d_out

  k_init<<<dim3(1), dim3(64), 0, stream>>>(amaxU);
  k_amax_in<<<dim3(1024, 1, 3), dim3(256), 0, stream>>>(query, key, value, nIn, amaxU);
  k_amax_w<<<dim3(128, 1, 4), dim3(256), 0, stream>>>(Wq, Wk, Wv, Wp, nW, amaxU);
  k_quant_in<<<dim3(1024, 1, 3), dim3(256), 0, stream>>>(query, key, value, qi, nIn, amaxU);
  k_quant_w<<<dim3(128, 1, 4), dim3(256), 0, stream>>>(Wq, Wk, Wv, Wp,
                                                       (signed char*)(ws + OFF_W), nW, amaxU);

  k_proj_i8<<<dim3(8, 128, 3), dim3(256), 0, stream>>>(ws, qi, bq, bk, bv);
  k_transpose<<<dim3(16, 32, 8), dim3(256), 0, stream>>>(ws);

  for (int b0 = 0; b0 < B_; b0 += 4) {
    k_scores<<<dim3(16, 16, 4), dim3(256), 0, stream>>>(ws, b0);
    k_softmax<<<dim3(8192), dim3(256), 0, stream>>>(ws);
    k_pv<<<dim3(8, 16, 4), dim3(256), 0, stream>>>(ws, b0);
  }

  k_quant8_f16<<<dim3(1024), dim3(256), 0, stream>>>(ws);
  k_final_i8<<<dim3(8, 128), dim3(256), 0, stream>>>(ws, bp, (float*)d_out);
}

// Round 5
// 503.359 us; speedup vs baseline: 2.4870x; 1.3033x over previous
//
#include <hip/hip_runtime.h>

// ---------------------------------------------------------------------------
// QuantizedAttention (B=8, S=2048, E=1024), no head split: scores are [B,S,S].
//   fused amax (block-reduced atomics) -> int8 quant (true div, bit-exact)
//   k_proj_i8: exact i8 MFMA GEMM (i32 acc) -> q,k,v fp16 planes  [T1 swizzle]
//   k_transpose: v -> vT [B][E][S] fp16
//   per 4-batch group:
//     k_scores z=4: 0.125 * qh@kh^T -> f32 scores (4 batches)     [T1 swizzle]
//     k_softmax: row softmax f32, P fp16 written IN-PLACE over scores + 1/sum
//     k_pv z=4: (P @ vT^T) * recip -> attn_out fp16 + f32 amax    [T1 swizzle]
//   quant attn_out -> int8 -> exact i8 MFMA final proj -> d_out   [T1 swizzle]
// Round-5 fix: one atomicMax per BLOCK (LDS reduce), not per wave — 12288
// same-line device atomics serialized ~169us in k_amax_in (r4 profile).
// Peak workspace ~196 MiB.
// ---------------------------------------------------------------------------

typedef __attribute__((ext_vector_type(4))) float f32x4;
typedef __attribute__((ext_vector_type(4))) int i32x4;
typedef __attribute__((ext_vector_type(8))) char s8x8;
typedef _Float16 f16;
typedef _Float16 half8 __attribute__((ext_vector_type(8)));
typedef _Float16 half4 __attribute__((ext_vector_type(4)));

#define DEVI static __device__ __forceinline__

constexpr int B_ = 8, S_ = 2048, E_ = 1024;
constexpr long NROW = (long)B_ * S_;  // 16384

constexpr size_t KB = 1024, MB = 1024 * 1024;
constexpr size_t OFF_SC  = 0;                     // u32[8] amax bits
constexpr size_t OFF_RS  = 1 * KB;                // 8192 f32 recip rowsums (4 batches)
constexpr size_t OFF_W   = 64 * KB;               // 4 weight planes int8, 1 MiB each
constexpr size_t SZ_WPL  = (size_t)E_ * E_;       // 1 MiB
constexpr size_t SZ_PL   = (size_t)NROW * E_ * 2; // 32 MiB (fp16 plane)
constexpr size_t OFF_QH  = OFF_W + 4 * SZ_WPL;
constexpr size_t OFF_KH  = OFF_QH + SZ_PL;
constexpr size_t OFF_VH  = OFF_KH + SZ_PL;        // later overlay: attn_out fp16
constexpr size_t OFF_VT  = OFF_VH + SZ_PL;        // V^T fp16 [B][E][S]
constexpr size_t OFF_SCB = OFF_VT + SZ_PL;        // scores f32, 4 batches, 64 MiB
constexpr size_t WS_NEED = OFF_SCB + 64 * MB;     // ~196.06 MiB
constexpr size_t OFF_AOQ = OFF_SCB;               // int8 attn_out (16 MiB overlay)

// ---- helpers ---------------------------------------------------------------
typedef const __attribute__((address_space(1))) void* gptr1;
typedef __attribute__((address_space(3))) void* lptr3;

DEVI void gload16(const void* g, void* l) {
  __builtin_amdgcn_global_load_lds((gptr1)g, (lptr3)l, 16, 0, 0);
}

DEVI f32x4 MF16(half8 a, half8 b, f32x4 c) {
  return __builtin_amdgcn_mfma_f32_16x16x32_f16(a, b, c, 0, 0, 0);
}
DEVI i32x4 MFI8(i32x4 a, i32x4 b, i32x4 c) {
  return __builtin_amdgcn_mfma_i32_16x16x64_i8(a, b, c, 0, 0, 0);
}

DEVI float scale_of(const unsigned int* amaxU, int idx) {
  return fmaxf(__uint_as_float(amaxU[idx]) / 127.f, 1e-8f);
}

DEVI signed char q8(float x, float s) {  // true division: bit-exact vs reference
  return (signed char)(int)fminf(fmaxf(rintf(x / s), -127.f), 127.f);
}

// T1 XCD-chunked swizzle: hardware id d (round-robin over 8 XCDs) -> work id w
DEVI int xcd_swz(int d, int n) { return (d & 7) * (n >> 3) + (d >> 3); }

// wave reduce-max then ONE atomic per block via LDS (avoids same-line
// atomic serialization: 12288 wave-atomics cost ~169us measured in r4)
DEVI void block_atomic_max(float m, unsigned int* dst) {
  __shared__ float red[4];
#pragma unroll
  for (int o = 32; o; o >>= 1) m = fmaxf(m, __shfl_xor(m, o));
  const int lane = threadIdx.x & 63, wid = threadIdx.x >> 6;
  if (lane == 0) red[wid] = m;
  __syncthreads();
  if (threadIdx.x == 0) {
    m = fmaxf(fmaxf(red[0], red[1]), fmaxf(red[2], red[3]));
    atomicMax(dst, __float_as_uint(m));
  }
}

// ---- small kernels ---------------------------------------------------------
__global__ void k_zero(float* o, long n) {
  long i = ((long)blockIdx.x * blockDim.x + threadIdx.x) * 4;
  const long stride = (long)gridDim.x * blockDim.x * 4;
  for (; i < n; i += stride) {
    float4 z = {0.f, 0.f, 0.f, 0.f};
    *(float4*)(o + i) = z;
  }
}

__global__ void k_init(unsigned int* a) {
  if (threadIdx.x < 8) a[threadIdx.x] = 0u;
}

DEVI void amax_body(const float* __restrict__ x, long n, unsigned int* amaxU, int idx) {
  long i = ((long)blockIdx.x * blockDim.x + threadIdx.x) * 8;
  const long stride = (long)gridDim.x * blockDim.x * 8;
  float m = 0.f;
  for (; i < n; i += stride) {
    float4 a = *(const float4*)(x + i);
    float4 b = *(const float4*)(x + i + 4);
    m = fmaxf(m, fmaxf(fmaxf(fabsf(a.x), fabsf(a.y)), fmaxf(fabsf(a.z), fabsf(a.w))));
    m = fmaxf(m, fmaxf(fmaxf(fabsf(b.x), fabsf(b.y)), fmaxf(fabsf(b.z), fabsf(b.w))));
  }
  block_atomic_max(m, amaxU + idx);
}

__global__ void k_amax_in(const float* __restrict__ q, const float* __restrict__ k,
                          const float* __restrict__ v, long n, unsigned int* amaxU) {
  const int z = blockIdx.z;
  amax_body(z == 0 ? q : (z == 1 ? k : v), n, amaxU, z);
}
__global__ void k_amax_w(const float* __restrict__ a, const float* __restrict__ b,
                         const float* __restrict__ c, const float* __restrict__ d,
                         long n, unsigned int* amaxU) {
  const int z = blockIdx.z;
  amax_body(z == 0 ? a : (z == 1 ? b : (z == 2 ? c : d)), n, amaxU, 3 + z);
}

DEVI void quant8_body(const float* __restrict__ x, signed char* __restrict__ q, long n,
                      float s) {
  long i = ((long)blockIdx.x * blockDim.x + threadIdx.x) * 8;
  const long stride = (long)gridDim.x * blockDim.x * 8;
  for (; i < n; i += stride) {
    float4 a = *(const float4*)(x + i);
    float4 b = *(const float4*)(x + i + 4);
    s8x8 o;
    o[0] = q8(a.x, s); o[1] = q8(a.y, s); o[2] = q8(a.z, s); o[3] = q8(a.w, s);
    o[4] = q8(b.x, s); o[5] = q8(b.y, s); o[6] = q8(b.z, s); o[7] = q8(b.w, s);
    *(s8x8*)(q + i) = o;
  }
}

__global__ void k_quant_in(const float* __restrict__ q, const float* __restrict__ k,
                           const float* __restrict__ v, signed char* __restrict__ out,
                           long n, const unsigned int* __restrict__ amaxU) {
  const int z = blockIdx.z;
  quant8_body(z == 0 ? q : (z == 1 ? k : v), out + (size_t)z * n, n, scale_of(amaxU, z));
}
__global__ void k_quant_w(const float* __restrict__ a, const float* __restrict__ b,
                          const float* __restrict__ c, const float* __restrict__ d,
                          signed char* __restrict__ out, long n,
                          const unsigned int* __restrict__ amaxU) {
  const int z = blockIdx.z;
  quant8_body(z == 0 ? a : (z == 1 ? b : (z == 2 ? c : d)), out + (size_t)z * n, n,
              scale_of(amaxU, 3 + z));
}

// attn_out fp16 -> int8
__global__ void k_quant8_f16(char* __restrict__ ws) {
  const unsigned int* amaxU = (const unsigned int*)(ws + OFF_SC);
  const float s = scale_of(amaxU, 7);
  const f16* x = (const f16*)(ws + OFF_VH);
  signed char* o = (signed char*)(ws + OFF_AOQ);
  const long n = NROW * E_;
  long i = ((long)blockIdx.x * blockDim.x + threadIdx.x) * 8;
  const long stride = (long)gridDim.x * blockDim.x * 8;
  for (; i < n; i += stride) {
    half8 v = *(const half8*)(x + i);
    s8x8 w;
#pragma unroll
    for (int j = 0; j < 8; ++j) w[j] = q8((float)v[j], s);
    *(s8x8*)(o + i) = w;
  }
}

// ---- i8 GEMM core: C(128x128) = A(128xK)i8 @ B(128xK)i8^T, BK=128 ----------
DEVI void gemm_core_i8(const signed char* __restrict__ A, const signed char* __restrict__ Bm,
                       int lda, int K, signed char* ldsA, signed char* ldsB,
                       i32x4 acc[4][4], int tid) {
  const int lane = tid & 63, wid = tid >> 6;
  const int wm = wid >> 1, wn = wid & 1;
  const int frow = lane & 15;
  const int fko = (lane >> 4) * 16;
  for (int k0 = 0; k0 < K; k0 += 128) {
    __syncthreads();
#pragma unroll
    for (int it = 0; it < 4; ++it) {
      int c = it * 256 + tid;
      int row = c >> 3, cc = c & 7;
      int lb = (it * 256 + (tid & 192)) * 16;
      gload16(A + (long)row * lda + k0 + cc * 16, ldsA + lb);
      gload16(Bm + (long)row * lda + k0 + cc * 16, ldsB + lb);
    }
    __syncthreads();
#pragma unroll
    for (int kc = 0; kc < 2; ++kc) {
      i32x4 a[4], b[4];
#pragma unroll
      for (int m = 0; m < 4; ++m)
        a[m] = *(const i32x4*)(ldsA + (wm * 64 + m * 16 + frow) * 128 + kc * 64 + fko);
#pragma unroll
      for (int n = 0; n < 4; ++n)
        b[n] = *(const i32x4*)(ldsB + (wn * 64 + n * 16 + frow) * 128 + kc * 64 + fko);
#pragma unroll
      for (int m = 0; m < 4; ++m)
#pragma unroll
        for (int n = 0; n < 4; ++n)
          acc[m][n] = MFI8(a[m], b[n], acc[m][n]);
    }
  }
}

// ---- fp16 GEMM core: C(128x128) = A(128xK) @ B(128xK)^T, BK=64 -------------
DEVI void gemm_core_f16(const unsigned short* __restrict__ A,
                        const unsigned short* __restrict__ Bm, int lda, int ldb, int K,
                        unsigned short* ldsA, unsigned short* ldsB, f32x4 acc[4][4], int tid) {
  const int lane = tid & 63, wid = tid >> 6;
  const int wm = wid >> 1, wn = wid & 1;
  const int frow = lane & 15;
  const int fko = (lane >> 4) * 8;
  for (int k0 = 0; k0 < K; k0 += 64) {
    __syncthreads();
#pragma unroll
    for (int it = 0; it < 4; ++it) {
      int c = it * 256 + tid;
      int row = c >> 3, cc = c & 7;
      int lb = (it * 256 + (tid & 192)) * 8;
      gload16(A + (long)row * lda + k0 + cc * 8, ldsA + lb);
      gload16(Bm + (long)row * ldb + k0 + cc * 8, ldsB + lb);
    }
    __syncthreads();
#pragma unroll
    for (int kc = 0; kc < 2; ++kc) {
      half8 a[4], b[4];
#pragma unroll
      for (int m = 0; m < 4; ++m)
        a[m] = *(const half8*)(ldsA + (wm * 64 + m * 16 + frow) * 64 + kc * 32 + fko);
#pragma unroll
      for (int n = 0; n < 4; ++n)
        b[n] = *(const half8*)(ldsB + (wn * 64 + n * 16 + frow) * 64 + kc * 32 + fko);
#pragma unroll
      for (int m = 0; m < 4; ++m)
#pragma unroll
        for (int n = 0; n < 4; ++n)
          acc[m][n] = MF16(a[m], b[n], acc[m][n]);
    }
  }
}

// ---- projections: exact i8 GEMM -> fp16 planes -----------------------------
__global__ __launch_bounds__(256, 2) void k_proj_i8(char* __restrict__ ws,
                                                    const signed char* __restrict__ qi,
                                                    const float* __restrict__ bq,
                                                    const float* __restrict__ bk,
                                                    const float* __restrict__ bv) {
  __shared__ __attribute__((aligned(16))) signed char lA[128 * 128], lB[128 * 128];
  const int tid = threadIdx.x;
  int d = blockIdx.x + 8 * blockIdx.y + 1024 * blockIdx.z;
  int w = xcd_swz(d, 3072);
  const int bx = w & 7, by = (w >> 3) & 127, z = w >> 10;
  const unsigned int* amaxU = (const unsigned int*)(ws + OFF_SC);
  const signed char* A = qi + (size_t)z * NROW * E_ + (size_t)by * 128 * E_;
  const signed char* Bm =
      (const signed char*)(ws + OFF_W + (size_t)z * SZ_WPL) + (size_t)bx * 128 * E_;
  f16* H = (f16*)(ws + OFF_QH + (size_t)z * SZ_PL);
  const float* bias = (z == 0) ? bq : ((z == 1) ? bk : bv);
  const float sc = scale_of(amaxU, z) * scale_of(amaxU, 3 + z);
  i32x4 acc[4][4] = {};
  gemm_core_i8(A, Bm, E_, E_, lA, lB, acc, tid);
  const int lane = tid & 63, wid = tid >> 6, wm = wid >> 1, wn = wid & 1;
  const long r0 = (long)by * 128 + wm * 64;
  const int c0 = bx * 128 + wn * 64;
#pragma unroll
  for (int m = 0; m < 4; ++m)
#pragma unroll
    for (int n = 0; n < 4; ++n) {
      int col = c0 + n * 16 + (lane & 15);
      float bc = bias[col];
#pragma unroll
      for (int r = 0; r < 4; ++r) {
        long row = r0 + m * 16 + (lane >> 4) * 4 + r;
        H[row * E_ + col] = (f16)(sc * (float)acc[m][n][r] + bc);
      }
    }
}

// ---- V transpose: vh [b][s][e] -> vT [b][e][s] -----------------------------
__global__ void k_transpose(char* __restrict__ ws) {
  __shared__ f16 t[64][72];
  const int b = blockIdx.z, e0 = blockIdx.x * 64, s0 = blockIdx.y * 64;
  const f16* V = (const f16*)(ws + OFF_VH) + (size_t)b * S_ * E_;
  f16* VT = (f16*)(ws + OFF_VT) + (size_t)b * E_ * S_;
  const int tid = threadIdx.x;
  const int r = tid >> 2, cc = (tid & 3) * 16;
#pragma unroll
  for (int j = 0; j < 2; ++j) {
    half8 v = *(const half8*)(V + (size_t)(s0 + r) * E_ + e0 + cc + j * 8);
#pragma unroll
    for (int q = 0; q < 8; ++q) t[cc + j * 8 + q][r] = v[q];
  }
  __syncthreads();
#pragma unroll
  for (int j = 0; j < 2; ++j) {
    half8 w;
#pragma unroll
    for (int q = 0; q < 8; ++q) w[q] = t[r][cc + j * 8 + q];
    *(half8*)(VT + (size_t)(e0 + r) * S_ + s0 + cc + j * 8) = w;
  }
}

// ---- scores (4-batch group): C = 0.125 * qh@kh^T, fp16 MFMA ----------------
__global__ __launch_bounds__(256, 2) void k_scores(char* __restrict__ ws, int b0) {
  __shared__ __attribute__((aligned(16))) unsigned short lA[128 * 64], lB[128 * 64];
  const int tid = threadIdx.x;
  int d = blockIdx.x + 16 * blockIdx.y + 256 * blockIdx.z;
  int w = xcd_swz(d, 1024);
  const int bx = w & 15, by = (w >> 4) & 15, zb = w >> 8;
  const int b = b0 + zb;
  const unsigned short* A =
      (const unsigned short*)(ws + OFF_QH) + ((size_t)b * S_ + (size_t)by * 128) * E_;
  const unsigned short* Bm =
      (const unsigned short*)(ws + OFF_KH) + ((size_t)b * S_ + (size_t)bx * 128) * E_;
  float* C = (float*)(ws + OFF_SCB) + (size_t)zb * S_ * S_;
  f32x4 acc[4][4] = {};
  gemm_core_f16(A, Bm, E_, E_, E_, lA, lB, acc, tid);
  const int lane = tid & 63, wid = tid >> 6, wm = wid >> 1, wn = wid & 1;
  const int r0 = by * 128 + wm * 64;
  const int c0 = bx * 128 + wn * 64;
#pragma unroll
  for (int m = 0; m < 4; ++m)
#pragma unroll
    for (int n = 0; n < 4; ++n) {
      int col = c0 + n * 16 + (lane & 15);
#pragma unroll
      for (int r = 0; r < 4; ++r) {
        int row = r0 + m * 16 + (lane >> 4) * 4 + r;
        C[(size_t)row * S_ + col] = 0.125f * acc[m][n][r];
      }
    }
}

// ---- row softmax (4-batch group), P fp16 written IN-PLACE over scores ------
__global__ __launch_bounds__(256) void k_softmax(char* __restrict__ ws) {
  const long row = blockIdx.x;  // 0..8191 (4 batches)
  float* src = (float*)(ws + OFF_SCB) + row * S_;
  f16* P = (f16*)src;
  float* RS = (float*)(ws + OFF_RS);
  const int tid = threadIdx.x, lane = tid & 63, wid = tid >> 6;
  float4 v0 = ((const float4*)src)[tid];
  float4 v1 = ((const float4*)src)[tid + 256];
  float m = fmaxf(fmaxf(fmaxf(v0.x, v0.y), fmaxf(v0.z, v0.w)),
                  fmaxf(fmaxf(v1.x, v1.y), fmaxf(v1.z, v1.w)));
#pragma unroll
  for (int o = 32; o; o >>= 1) m = fmaxf(m, __shfl_xor(m, o));
  __shared__ float redm[4], reds[4];
  if (lane == 0) redm[wid] = m;
  __syncthreads();
  m = fmaxf(fmaxf(redm[0], redm[1]), fmaxf(redm[2], redm[3]));
  float e0 = expf(v0.x - m), e1 = expf(v0.y - m), e2 = expf(v0.z - m), e3 = expf(v0.w - m);
  float e4 = expf(v1.x - m), e5 = expf(v1.y - m), e6 = expf(v1.z - m), e7 = expf(v1.w - m);
  float s = ((e0 + e1) + (e2 + e3)) + ((e4 + e5) + (e6 + e7));
#pragma unroll
  for (int o = 32; o; o >>= 1) s += __shfl_xor(s, o);
  if (lane == 0) reds[wid] = s;
  __syncthreads();
  s = (reds[0] + reds[1]) + (reds[2] + reds[3]);
  if (tid == 0) RS[row] = 1.f / s;
  half4 p0 = {(f16)e0, (f16)e1, (f16)e2, (f16)e3};
  half4 p1 = {(f16)e4, (f16)e5, (f16)e6, (f16)e7};
  *(half4*)(P + (long)tid * 4) = p0;
  *(half4*)(P + 1024 + (long)tid * 4) = p1;
}

// ---- PV (4-batch group): attn_out = (P @ vT^T) * recip -> fp16 + f32 amax --
__global__ __launch_bounds__(256, 2) void k_pv(char* __restrict__ ws, int b0) {
  __shared__ __attribute__((aligned(16))) unsigned short lA[128 * 64], lB[128 * 64];
  const int tid = threadIdx.x;
  int d = blockIdx.x + 8 * blockIdx.y + 128 * blockIdx.z;
  int w = xcd_swz(d, 512);
  const int bx = w & 7, by = (w >> 3) & 15, zb = w >> 7;
  const int b = b0 + zb;
  // P in-place over scores: fp16 data at row pitch 2*S_ elements
  const unsigned short* A = (const unsigned short*)((float*)(ws + OFF_SCB) +
                                                    (size_t)zb * S_ * S_) +
                            (size_t)by * 128 * (2 * S_);
  const unsigned short* Bm = (const unsigned short*)(ws + OFF_VT) + (size_t)b * E_ * S_ +
                             (size_t)bx * 128 * S_;
  f32x4 acc[4][4] = {};
  gemm_core_f16(A, Bm, 2 * S_, S_, S_, lA, lB, acc, tid);
  const float* RS = (const float*)(ws + OFF_RS) + (size_t)zb * S_;
  f16* O = (f16*)(ws + OFF_VH) + (size_t)b * S_ * E_;
  unsigned int* amaxU = (unsigned int*)(ws + OFF_SC);
  const int lane = tid & 63, wid = tid >> 6, wm = wid >> 1, wn = wid & 1;
  const int r0 = by * 128 + wm * 64;
  const int c0 = bx * 128 + wn * 64;
  float mx = 0.f;
#pragma unroll
  for (int m = 0; m < 4; ++m)
#pragma unroll
    for (int n = 0; n < 4; ++n) {
      int col = c0 + n * 16 + (lane & 15);
#pragma unroll
      for (int r = 0; r < 4; ++r) {
        int row = r0 + m * 16 + (lane >> 4) * 4 + r;
        float o = acc[m][n][r] * RS[row];
        O[(size_t)row * E_ + col] = (f16)o;
        mx = fmaxf(mx, fabsf(o));
      }
    }
  __syncthreads();  // lA/lB done; reuse of shared red[] in helper is fresh
  block_atomic_max(mx, amaxU + 7);
}

// ---- final projection: exact i8 GEMM -> d_out f32 --------------------------
__global__ __launch_bounds__(256, 2) void k_final_i8(char* __restrict__ ws,
                                                     const float* __restrict__ bp,
                                                     float* __restrict__ out) {
  __shared__ __attribute__((aligned(16))) signed char lA[128 * 128], lB[128 * 128];
  const int tid = threadIdx.x;
  int d = blockIdx.x + 8 * blockIdx.y;
  int w = xcd_swz(d, 1024);
  const int bx = w & 7, by = w >> 3;
  const unsigned int* amaxU = (const unsigned int*)(ws + OFF_SC);
  const signed char* A = (const signed char*)(ws + OFF_AOQ) + (size_t)by * 128 * E_;
  const signed char* Bm =
      (const signed char*)(ws + OFF_W + 3 * SZ_WPL) + (size_t)bx * 128 * E_;
  const float sc = scale_of(amaxU, 7) * scale_of(amaxU, 6);
  i32x4 acc[4][4] = {};
  gemm_core_i8(A, Bm, E_, E_, lA, lB, acc, tid);
  const int lane = tid & 63, wid = tid >> 6, wm = wid >> 1, wn = wid & 1;
  const long r0 = (long)by * 128 + wm * 64;
  const int c0 = bx * 128 + wn * 64;
#pragma unroll
  for (int m = 0; m < 4; ++m)
#pragma unroll
    for (int n = 0; n < 4; ++n) {
      int col = c0 + n * 16 + (lane & 15);
      float bc = bp[col];
#pragma unroll
      for (int r = 0; r < 4; ++r) {
        long row = r0 + m * 16 + (lane >> 4) * 4 + r;
        out[row * E_ + col] = sc * (float)acc[m][n][r] + bc;
      }
    }
}

// ---------------------------------------------------------------------------
extern "C" void kernel_launch(void* const* d_in, const int* in_sizes, int n_in,
                              void* d_out, int out_size, void* d_ws, size_t ws_size,
                              hipStream_t stream) {
  (void)in_sizes; (void)n_in; (void)out_size;
  char* ws = (char*)d_ws;
  const float* query = (const float*)d_in[0];
  const float* key   = (const float*)d_in[1];
  const float* value = (const float*)d_in[2];
  const float* Wq = (const float*)d_in[3];
  const float* bq = (const float*)d_in[4];
  const float* Wk = (const float*)d_in[5];
  const float* bk = (const float*)d_in[6];
  const float* Wv = (const float*)d_in[7];
  const float* bv = (const float*)d_in[8];
  const float* Wp = (const float*)d_in[9];
  const float* bp = (const float*)d_in[10];

  const long nIn = NROW * E_;  // 16,777,216
  const long nW = (long)E_ * E_;

  if (ws_size < WS_NEED) {  // diagnostic fallback: zeros, no OOB writes
    k_zero<<<dim3(2048), dim3(256), 0, stream>>>((float*)d_out, nIn);
    return;
  }

  unsigned int* amaxU = (unsigned int*)(ws + OFF_SC);
  signed char* qi = (signed char*)d_out;  // int8 q/k/v planes live in d_out

  k_init<<<dim3(1), dim3(64), 0, stream>>>(amaxU);
  k_amax_in<<<dim3(512, 1, 3), dim3(256), 0, stream>>>(query, key, value, nIn, amaxU);
  k_amax_w<<<dim3(64, 1, 4), dim3(256), 0, stream>>>(Wq, Wk, Wv, Wp, nW, amaxU);
  k_quant_in<<<dim3(1024, 1, 3), dim3(256), 0, stream>>>(query, key, value, qi, nIn, amaxU);
  k_quant_w<<<dim3(128, 1, 4), dim3(256), 0, stream>>>(Wq, Wk, Wv, Wp,
                                                       (signed char*)(ws + OFF_W), nW, amaxU);

  k_proj_i8<<<dim3(8, 128, 3), dim3(256), 0, stream>>>(ws, qi, bq, bk, bv);
  k_transpose<<<dim3(16, 32, 8), dim3(256), 0, stream>>>(ws);

  for (int b0 = 0; b0 < B_; b0 += 4) {
    k_scores<<<dim3(16, 16, 4), dim3(256), 0, stream>>>(ws, b0);
    k_softmax<<<dim3(8192), dim3(256), 0, stream>>>(ws);
    k_pv<<<dim3(8, 16, 4), dim3(256), 0, stream>>>(ws, b0);
  }

  k_quant8_f16<<<dim3(1024), dim3(256), 0, stream>>>(ws);
  k_final_i8<<<dim3(8, 128), dim3(256), 0, stream>>>(ws, bp, (float*)d_out);
}

// Round 6
// 455.594 us; speedup vs baseline: 2.7478x; 1.1048x over previous
//
#include <hip/hip_runtime.h>

// ---------------------------------------------------------------------------
// QuantizedAttention (B=8, S=2048, E=1024), no head split: scores are [B,S,S].
//   fused amax (block-reduced atomics) -> int8 quant (true div, bit-exact)
//   k_proj_i8: exact i8 MFMA GEMM (i32 acc) -> q,k,v fp16 planes  [T1 swizzle]
//   k_transpose: v -> vT [B][E][S] fp16
//   SINGLE group (all 8 batches):
//     k_scores: 0.125 * qh@kh^T -> fp16 scores [B][S][S]          [T1 swizzle]
//     k_softmax: row softmax (f32 math, fp16 in/out), P in-place + 1/rowsum
//     k_pv: (P @ vT^T) * recip -> attn_out fp16 + f32 amax        [T1 swizzle]
//   quant attn_out -> int8 -> exact i8 MFMA final proj -> d_out   [T1 swizzle]
// Round-6: all-batch attention middle (fp16 scores, 3 launches instead of 12;
// k_pv occupancy 2->4 blocks/CU). Peak workspace ~196 MiB (proven).
// ---------------------------------------------------------------------------

typedef __attribute__((ext_vector_type(4))) float f32x4;
typedef __attribute__((ext_vector_type(4))) int i32x4;
typedef __attribute__((ext_vector_type(8))) char s8x8;
typedef _Float16 f16;
typedef _Float16 half8 __attribute__((ext_vector_type(8)));

#define DEVI static __device__ __forceinline__

constexpr int B_ = 8, S_ = 2048, E_ = 1024;
constexpr long NROW = (long)B_ * S_;  // 16384

constexpr size_t KB = 1024, MB = 1024 * 1024;
constexpr size_t OFF_SC  = 0;                     // u32[8] amax bits
constexpr size_t OFF_RS  = 1 * KB;                // 16384 f32 recip rowsums (64 KiB)
constexpr size_t OFF_W   = 128 * KB;              // 4 weight planes int8, 1 MiB each
constexpr size_t SZ_WPL  = (size_t)E_ * E_;       // 1 MiB
constexpr size_t SZ_PL   = (size_t)NROW * E_ * 2; // 32 MiB (fp16 plane)
constexpr size_t OFF_QH  = OFF_W + 4 * SZ_WPL;
constexpr size_t OFF_KH  = OFF_QH + SZ_PL;
constexpr size_t OFF_VH  = OFF_KH + SZ_PL;        // later overlay: attn_out fp16
constexpr size_t OFF_VT  = OFF_VH + SZ_PL;        // V^T fp16 [B][E][S]
constexpr size_t OFF_SCB = OFF_VT + SZ_PL;        // scores fp16 [B][S][S], 64 MiB
constexpr size_t WS_NEED = OFF_SCB + 64 * MB;     // ~196.1 MiB
constexpr size_t OFF_AOQ = OFF_SCB;               // int8 attn_out (16 MiB overlay)

// ---- helpers ---------------------------------------------------------------
typedef const __attribute__((address_space(1))) void* gptr1;
typedef __attribute__((address_space(3))) void* lptr3;

DEVI void gload16(const void* g, void* l) {
  __builtin_amdgcn_global_load_lds((gptr1)g, (lptr3)l, 16, 0, 0);
}

DEVI f32x4 MF16(half8 a, half8 b, f32x4 c) {
  return __builtin_amdgcn_mfma_f32_16x16x32_f16(a, b, c, 0, 0, 0);
}
DEVI i32x4 MFI8(i32x4 a, i32x4 b, i32x4 c) {
  return __builtin_amdgcn_mfma_i32_16x16x64_i8(a, b, c, 0, 0, 0);
}

DEVI float scale_of(const unsigned int* amaxU, int idx) {
  return fmaxf(__uint_as_float(amaxU[idx]) / 127.f, 1e-8f);
}

DEVI signed char q8(float x, float s) {  // true division: bit-exact vs reference
  return (signed char)(int)fminf(fmaxf(rintf(x / s), -127.f), 127.f);
}

// T1 XCD-chunked swizzle: hardware id d (round-robin over 8 XCDs) -> work id w
DEVI int xcd_swz(int d, int n) { return (d & 7) * (n >> 3) + (d >> 3); }

// wave reduce-max then ONE atomic per block via LDS (r4 lesson: 12288
// same-line wave-atomics serialized ~169us)
DEVI void block_atomic_max(float m, unsigned int* dst) {
  __shared__ float red[4];
#pragma unroll
  for (int o = 32; o; o >>= 1) m = fmaxf(m, __shfl_xor(m, o));
  const int lane = threadIdx.x & 63, wid = threadIdx.x >> 6;
  if (lane == 0) red[wid] = m;
  __syncthreads();
  if (threadIdx.x == 0) {
    m = fmaxf(fmaxf(red[0], red[1]), fmaxf(red[2], red[3]));
    atomicMax(dst, __float_as_uint(m));
  }
}

// ---- small kernels ---------------------------------------------------------
__global__ void k_zero(float* o, long n) {
  long i = ((long)blockIdx.x * blockDim.x + threadIdx.x) * 4;
  const long stride = (long)gridDim.x * blockDim.x * 4;
  for (; i < n; i += stride) {
    float4 z = {0.f, 0.f, 0.f, 0.f};
    *(float4*)(o + i) = z;
  }
}

__global__ void k_init(unsigned int* a) {
  if (threadIdx.x < 8) a[threadIdx.x] = 0u;
}

DEVI void amax_body(const float* __restrict__ x, long n, unsigned int* amaxU, int idx) {
  long i = ((long)blockIdx.x * blockDim.x + threadIdx.x) * 8;
  const long stride = (long)gridDim.x * blockDim.x * 8;
  float m = 0.f;
  for (; i < n; i += stride) {
    float4 a = *(const float4*)(x + i);
    float4 b = *(const float4*)(x + i + 4);
    m = fmaxf(m, fmaxf(fmaxf(fabsf(a.x), fabsf(a.y)), fmaxf(fabsf(a.z), fabsf(a.w))));
    m = fmaxf(m, fmaxf(fmaxf(fabsf(b.x), fabsf(b.y)), fmaxf(fabsf(b.z), fabsf(b.w))));
  }
  block_atomic_max(m, amaxU + idx);
}

__global__ void k_amax_in(const float* __restrict__ q, const float* __restrict__ k,
                          const float* __restrict__ v, long n, unsigned int* amaxU) {
  const int z = blockIdx.z;
  amax_body(z == 0 ? q : (z == 1 ? k : v), n, amaxU, z);
}
__global__ void k_amax_w(const float* __restrict__ a, const float* __restrict__ b,
                         const float* __restrict__ c, const float* __restrict__ d,
                         long n, unsigned int* amaxU) {
  const int z = blockIdx.z;
  amax_body(z == 0 ? a : (z == 1 ? b : (z == 2 ? c : d)), n, amaxU, 3 + z);
}

DEVI void quant8_body(const float* __restrict__ x, signed char* __restrict__ q, long n,
                      float s) {
  long i = ((long)blockIdx.x * blockDim.x + threadIdx.x) * 8;
  const long stride = (long)gridDim.x * blockDim.x * 8;
  for (; i < n; i += stride) {
    float4 a = *(const float4*)(x + i);
    float4 b = *(const float4*)(x + i + 4);
    s8x8 o;
    o[0] = q8(a.x, s); o[1] = q8(a.y, s); o[2] = q8(a.z, s); o[3] = q8(a.w, s);
    o[4] = q8(b.x, s); o[5] = q8(b.y, s); o[6] = q8(b.z, s); o[7] = q8(b.w, s);
    *(s8x8*)(q + i) = o;
  }
}

__global__ void k_quant_in(const float* __restrict__ q, const float* __restrict__ k,
                           const float* __restrict__ v, signed char* __restrict__ out,
                           long n, const unsigned int* __restrict__ amaxU) {
  const int z = blockIdx.z;
  quant8_body(z == 0 ? q : (z == 1 ? k : v), out + (size_t)z * n, n, scale_of(amaxU, z));
}
__global__ void k_quant_w(const float* __restrict__ a, const float* __restrict__ b,
                          const float* __restrict__ c, const float* __restrict__ d,
                          signed char* __restrict__ out, long n,
                          const unsigned int* __restrict__ amaxU) {
  const int z = blockIdx.z;
  quant8_body(z == 0 ? a : (z == 1 ? b : (z == 2 ? c : d)), out + (size_t)z * n, n,
              scale_of(amaxU, 3 + z));
}

// attn_out fp16 -> int8
__global__ void k_quant8_f16(char* __restrict__ ws) {
  const unsigned int* amaxU = (const unsigned int*)(ws + OFF_SC);
  const float s = scale_of(amaxU, 7);
  const f16* x = (const f16*)(ws + OFF_VH);
  signed char* o = (signed char*)(ws + OFF_AOQ);
  const long n = NROW * E_;
  long i = ((long)blockIdx.x * blockDim.x + threadIdx.x) * 8;
  const long stride = (long)gridDim.x * blockDim.x * 8;
  for (; i < n; i += stride) {
    half8 v = *(const half8*)(x + i);
    s8x8 w;
#pragma unroll
    for (int j = 0; j < 8; ++j) w[j] = q8((float)v[j], s);
    *(s8x8*)(o + i) = w;
  }
}

// ---- i8 GEMM core: C(128x128) = A(128xK)i8 @ B(128xK)i8^T, BK=128 ----------
DEVI void gemm_core_i8(const signed char* __restrict__ A, const signed char* __restrict__ Bm,
                       int lda, int K, signed char* ldsA, signed char* ldsB,
                       i32x4 acc[4][4], int tid) {
  const int lane = tid & 63, wid = tid >> 6;
  const int wm = wid >> 1, wn = wid & 1;
  const int frow = lane & 15;
  const int fko = (lane >> 4) * 16;
  for (int k0 = 0; k0 < K; k0 += 128) {
    __syncthreads();
#pragma unroll
    for (int it = 0; it < 4; ++it) {
      int c = it * 256 + tid;
      int row = c >> 3, cc = c & 7;
      int lb = (it * 256 + (tid & 192)) * 16;
      gload16(A + (long)row * lda + k0 + cc * 16, ldsA + lb);
      gload16(Bm + (long)row * lda + k0 + cc * 16, ldsB + lb);
    }
    __syncthreads();
#pragma unroll
    for (int kc = 0; kc < 2; ++kc) {
      i32x4 a[4], b[4];
#pragma unroll
      for (int m = 0; m < 4; ++m)
        a[m] = *(const i32x4*)(ldsA + (wm * 64 + m * 16 + frow) * 128 + kc * 64 + fko);
#pragma unroll
      for (int n = 0; n < 4; ++n)
        b[n] = *(const i32x4*)(ldsB + (wn * 64 + n * 16 + frow) * 128 + kc * 64 + fko);
#pragma unroll
      for (int m = 0; m < 4; ++m)
#pragma unroll
        for (int n = 0; n < 4; ++n)
          acc[m][n] = MFI8(a[m], b[n], acc[m][n]);
    }
  }
}

// ---- fp16 GEMM core: C(128x128) = A(128xK) @ B(128xK)^T, BK=64 -------------
DEVI void gemm_core_f16(const unsigned short* __restrict__ A,
                        const unsigned short* __restrict__ Bm, int lda, int ldb, int K,
                        unsigned short* ldsA, unsigned short* ldsB, f32x4 acc[4][4], int tid) {
  const int lane = tid & 63, wid = tid >> 6;
  const int wm = wid >> 1, wn = wid & 1;
  const int frow = lane & 15;
  const int fko = (lane >> 4) * 8;
  for (int k0 = 0; k0 < K; k0 += 64) {
    __syncthreads();
#pragma unroll
    for (int it = 0; it < 4; ++it) {
      int c = it * 256 + tid;
      int row = c >> 3, cc = c & 7;
      int lb = (it * 256 + (tid & 192)) * 8;
      gload16(A + (long)row * lda + k0 + cc * 8, ldsA + lb);
      gload16(Bm + (long)row * ldb + k0 + cc * 8, ldsB + lb);
    }
    __syncthreads();
#pragma unroll
    for (int kc = 0; kc < 2; ++kc) {
      half8 a[4], b[4];
#pragma unroll
      for (int m = 0; m < 4; ++m)
        a[m] = *(const half8*)(ldsA + (wm * 64 + m * 16 + frow) * 64 + kc * 32 + fko);
#pragma unroll
      for (int n = 0; n < 4; ++n)
        b[n] = *(const half8*)(ldsB + (wn * 64 + n * 16 + frow) * 64 + kc * 32 + fko);
#pragma unroll
      for (int m = 0; m < 4; ++m)
#pragma unroll
        for (int n = 0; n < 4; ++n)
          acc[m][n] = MF16(a[m], b[n], acc[m][n]);
    }
  }
}

// ---- projections: exact i8 GEMM -> fp16 planes -----------------------------
__global__ __launch_bounds__(256, 2) void k_proj_i8(char* __restrict__ ws,
                                                    const signed char* __restrict__ qi,
                                                    const float* __restrict__ bq,
                                                    const float* __restrict__ bk,
                                                    const float* __restrict__ bv) {
  __shared__ __attribute__((aligned(16))) signed char lA[128 * 128], lB[128 * 128];
  const int tid = threadIdx.x;
  int d = blockIdx.x + 8 * blockIdx.y + 1024 * blockIdx.z;
  int w = xcd_swz(d, 3072);
  const int bx = w & 7, by = (w >> 3) & 127, z = w >> 10;
  const unsigned int* amaxU = (const unsigned int*)(ws + OFF_SC);
  const signed char* A = qi + (size_t)z * NROW * E_ + (size_t)by * 128 * E_;
  const signed char* Bm =
      (const signed char*)(ws + OFF_W + (size_t)z * SZ_WPL) + (size_t)bx * 128 * E_;
  f16* H = (f16*)(ws + OFF_QH + (size_t)z * SZ_PL);
  const float* bias = (z == 0) ? bq : ((z == 1) ? bk : bv);
  const float sc = scale_of(amaxU, z) * scale_of(amaxU, 3 + z);
  i32x4 acc[4][4] = {};
  gemm_core_i8(A, Bm, E_, E_, lA, lB, acc, tid);
  const int lane = tid & 63, wid = tid >> 6, wm = wid >> 1, wn = wid & 1;
  const long r0 = (long)by * 128 + wm * 64;
  const int c0 = bx * 128 + wn * 64;
#pragma unroll
  for (int m = 0; m < 4; ++m)
#pragma unroll
    for (int n = 0; n < 4; ++n) {
      int col = c0 + n * 16 + (lane & 15);
      float bc = bias[col];
#pragma unroll
      for (int r = 0; r < 4; ++r) {
        long row = r0 + m * 16 + (lane >> 4) * 4 + r;
        H[row * E_ + col] = (f16)(sc * (float)acc[m][n][r] + bc);
      }
    }
}

// ---- V transpose: vh [b][s][e] -> vT [b][e][s] -----------------------------
__global__ void k_transpose(char* __restrict__ ws) {
  __shared__ f16 t[64][72];
  const int b = blockIdx.z, e0 = blockIdx.x * 64, s0 = blockIdx.y * 64;
  const f16* V = (const f16*)(ws + OFF_VH) + (size_t)b * S_ * E_;
  f16* VT = (f16*)(ws + OFF_VT) + (size_t)b * E_ * S_;
  const int tid = threadIdx.x;
  const int r = tid >> 2, cc = (tid & 3) * 16;
#pragma unroll
  for (int j = 0; j < 2; ++j) {
    half8 v = *(const half8*)(V + (size_t)(s0 + r) * E_ + e0 + cc + j * 8);
#pragma unroll
    for (int q = 0; q < 8; ++q) t[cc + j * 8 + q][r] = v[q];
  }
  __syncthreads();
#pragma unroll
  for (int j = 0; j < 2; ++j) {
    half8 w;
#pragma unroll
    for (int q = 0; q < 8; ++q) w[q] = t[r][cc + j * 8 + q];
    *(half8*)(VT + (size_t)(e0 + r) * S_ + s0 + cc + j * 8) = w;
  }
}

// ---- scores (all batches): S = 0.125 * qh@kh^T -> fp16 ---------------------
__global__ __launch_bounds__(256, 2) void k_scores(char* __restrict__ ws) {
  __shared__ __attribute__((aligned(16))) unsigned short lA[128 * 64], lB[128 * 64];
  const int tid = threadIdx.x;
  int d = blockIdx.x + 16 * blockIdx.y + 256 * blockIdx.z;
  int w = xcd_swz(d, 2048);
  const int bx = w & 15, by = (w >> 4) & 15, b = w >> 8;
  const unsigned short* A =
      (const unsigned short*)(ws + OFF_QH) + ((size_t)b * S_ + (size_t)by * 128) * E_;
  const unsigned short* Bm =
      (const unsigned short*)(ws + OFF_KH) + ((size_t)b * S_ + (size_t)bx * 128) * E_;
  f16* C = (f16*)(ws + OFF_SCB) + (size_t)b * S_ * S_;
  f32x4 acc[4][4] = {};
  gemm_core_f16(A, Bm, E_, E_, E_, lA, lB, acc, tid);
  const int lane = tid & 63, wid = tid >> 6, wm = wid >> 1, wn = wid & 1;
  const int r0 = by * 128 + wm * 64;
  const int c0 = bx * 128 + wn * 64;
#pragma unroll
  for (int m = 0; m < 4; ++m)
#pragma unroll
    for (int n = 0; n < 4; ++n) {
      int col = c0 + n * 16 + (lane & 15);
#pragma unroll
      for (int r = 0; r < 4; ++r) {
        int row = r0 + m * 16 + (lane >> 4) * 4 + r;
        C[(size_t)row * S_ + col] = (f16)(0.125f * acc[m][n][r]);
      }
    }
}

// ---- row softmax (all batches): fp16 in/out, f32 math, P in-place + 1/sum --
__global__ __launch_bounds__(256) void k_softmax(char* __restrict__ ws) {
  const long row = blockIdx.x;  // 0..16383
  f16* src = (f16*)(ws + OFF_SCB) + row * S_;
  float* RS = (float*)(ws + OFF_RS);
  const int tid = threadIdx.x, lane = tid & 63, wid = tid >> 6;
  half8 v = *(const half8*)(src + (long)tid * 8);
  float x[8];
#pragma unroll
  for (int j = 0; j < 8; ++j) x[j] = (float)v[j];
  float m = x[0];
#pragma unroll
  for (int j = 1; j < 8; ++j) m = fmaxf(m, x[j]);
#pragma unroll
  for (int o = 32; o; o >>= 1) m = fmaxf(m, __shfl_xor(m, o));
  __shared__ float redm[4], reds[4];
  if (lane == 0) redm[wid] = m;
  __syncthreads();
  m = fmaxf(fmaxf(redm[0], redm[1]), fmaxf(redm[2], redm[3]));
  float e[8], s = 0.f;
#pragma unroll
  for (int j = 0; j < 8; ++j) {
    e[j] = expf(x[j] - m);
    s += e[j];
  }
#pragma unroll
  for (int o = 32; o; o >>= 1) s += __shfl_xor(s, o);
  if (lane == 0) reds[wid] = s;
  __syncthreads();
  s = (reds[0] + reds[1]) + (reds[2] + reds[3]);
  if (tid == 0) RS[row] = 1.f / s;
  half8 p;
#pragma unroll
  for (int j = 0; j < 8; ++j) p[j] = (f16)e[j];
  *(half8*)(src + (long)tid * 8) = p;
}

// ---- PV (all batches): attn_out = (P @ vT^T) * recip -> fp16 + f32 amax ----
__global__ __launch_bounds__(256, 2) void k_pv(char* __restrict__ ws) {
  __shared__ __attribute__((aligned(16))) unsigned short lA[128 * 64], lB[128 * 64];
  const int tid = threadIdx.x;
  int d = blockIdx.x + 8 * blockIdx.y + 128 * blockIdx.z;
  int w = xcd_swz(d, 1024);
  const int bx = w & 7, by = (w >> 3) & 15, b = w >> 7;
  const unsigned short* A = (const unsigned short*)(ws + OFF_SCB) + (size_t)b * S_ * S_ +
                            (size_t)by * 128 * S_;
  const unsigned short* Bm = (const unsigned short*)(ws + OFF_VT) + (size_t)b * E_ * S_ +
                             (size_t)bx * 128 * S_;
  f32x4 acc[4][4] = {};
  gemm_core_f16(A, Bm, S_, S_, S_, lA, lB, acc, tid);
  const float* RS = (const float*)(ws + OFF_RS) + (size_t)b * S_;
  f16* O = (f16*)(ws + OFF_VH) + (size_t)b * S_ * E_;
  unsigned int* amaxU = (unsigned int*)(ws + OFF_SC);
  const int lane = tid & 63, wid = tid >> 6, wm = wid >> 1, wn = wid & 1;
  const int r0 = by * 128 + wm * 64;
  const int c0 = bx * 128 + wn * 64;
  float mx = 0.f;
#pragma unroll
  for (int m = 0; m < 4; ++m)
#pragma unroll
    for (int n = 0; n < 4; ++n) {
      int col = c0 + n * 16 + (lane & 15);
#pragma unroll
      for (int r = 0; r < 4; ++r) {
        int row = r0 + m * 16 + (lane >> 4) * 4 + r;
        float o = acc[m][n][r] * RS[row];
        O[(size_t)row * E_ + col] = (f16)o;
        mx = fmaxf(mx, fabsf(o));
      }
    }
  __syncthreads();  // lA/lB done; shared red[] in helper is fresh
  block_atomic_max(mx, amaxU + 7);
}

// ---- final projection: exact i8 GEMM -> d_out f32 --------------------------
__global__ __launch_bounds__(256, 2) void k_final_i8(char* __restrict__ ws,
                                                     const float* __restrict__ bp,
                                                     float* __restrict__ out) {
  __shared__ __attribute__((aligned(16))) signed char lA[128 * 128], lB[128 * 128];
  const int tid = threadIdx.x;
  int d = blockIdx.x + 8 * blockIdx.y;
  int w = xcd_swz(d, 1024);
  const int bx = w & 7, by = w >> 3;
  const unsigned int* amaxU = (const unsigned int*)(ws + OFF_SC);
  const signed char* A = (const signed char*)(ws + OFF_AOQ) + (size_t)by * 128 * E_;
  const signed char* Bm =
      (const signed char*)(ws + OFF_W + 3 * SZ_WPL) + (size_t)bx * 128 * E_;
  const float sc = scale_of(amaxU, 7) * scale_of(amaxU, 6);
  i32x4 acc[4][4] = {};
  gemm_core_i8(A, Bm, E_, E_, lA, lB, acc, tid);
  const int lane = tid & 63, wid = tid >> 6, wm = wid >> 1, wn = wid & 1;
  const long r0 = (long)by * 128 + wm * 64;
  const int c0 = bx * 128 + wn * 64;
#pragma unroll
  for (int m = 0; m < 4; ++m)
#pragma unroll
    for (int n = 0; n < 4; ++n) {
      int col = c0 + n * 16 + (lane & 15);
      float bc = bp[col];
#pragma unroll
      for (int r = 0; r < 4; ++r) {
        long row = r0 + m * 16 + (lane >> 4) * 4 + r;
        out[row * E_ + col] = sc * (float)acc[m][n][r] + bc;
      }
    }
}

// ---------------------------------------------------------------------------
extern "C" void kernel_launch(void* const* d_in, const int* in_sizes, int n_in,
                              void* d_out, int out_size, void* d_ws, size_t ws_size,
                              hipStream_t stream) {
  (void)in_sizes; (void)n_in; (void)out_size;
  char* ws = (char*)d_ws;
  const float* query = (const float*)d_in[0];
  const float* key   = (const float*)d_in[1];
  const float* value = (const float*)d_in[2];
  const float* Wq = (const float*)d_in[3];
  const float* bq = (const float*)d_in[4];
  const float* Wk = (const float*)d_in[5];
  const float* bk = (const float*)d_in[6];
  const float* Wv = (const float*)d_in[7];
  const float* bv = (const float*)d_in[8];
  const float* Wp = (const float*)d_in[9];
  const float* bp = (const float*)d_in[10];

  const long nIn = NROW * E_;  // 16,777,216
  const long nW = (long)E_ * E_;

  if (ws_size < WS_NEED) {  // diagnostic fallback: zeros, no OOB writes
    k_zero<<<dim3(2048), dim3(256), 0, stream>>>((float*)d_out, nIn);
    return;
  }

  unsigned int* amaxU = (unsigned int*)(ws + OFF_SC);
  signed char* qi = (signed char*)d_out;  // int8 q/k/v planes live in d_out

  k_init<<<dim3(1), dim3(64), 0, stream>>>(amaxU);
  k_amax_in<<<dim3(512, 1, 3), dim3(256), 0, stream>>>(query, key, value, nIn, amaxU);
  k_amax_w<<<dim3(64, 1, 4), dim3(256), 0, stream>>>(Wq, Wk, Wv, Wp, nW, amaxU);
  k_quant_in<<<dim3(1024, 1, 3), dim3(256), 0, stream>>>(query, key, value, qi, nIn, amaxU);
  k_quant_w<<<dim3(128, 1, 4), dim3(256), 0, stream>>>(Wq, Wk, Wv, Wp,
                                                       (signed char*)(ws + OFF_W), nW, amaxU);

  k_proj_i8<<<dim3(8, 128, 3), dim3(256), 0, stream>>>(ws, qi, bq, bk, bv);
  k_transpose<<<dim3(16, 32, 8), dim3(256), 0, stream>>>(ws);

  k_scores<<<dim3(16, 16, 8), dim3(256), 0, stream>>>(ws);
  k_softmax<<<dim3(16384), dim3(256), 0, stream>>>(ws);
  k_pv<<<dim3(8, 16, 8), dim3(256), 0, stream>>>(ws);

  k_quant8_f16<<<dim3(1024), dim3(256), 0, stream>>>(ws);
  k_final_i8<<<dim3(8, 128), dim3(256), 0, stream>>>(ws, bp, (float*)d_out);
}

// Round 7
// 424.475 us; speedup vs baseline: 2.9492x; 1.0733x over previous
//
#include <hip/hip_runtime.h>

// ---------------------------------------------------------------------------
// QuantizedAttention (B=8, S=2048, E=1024), no head split: scores are [B,S,S].
//   fused amax (block-reduced atomics) -> int8 quant (true div, bit-exact)
//   k_proj_i8: exact i8 MFMA GEMM (i32 acc) -> q,k,v fp16 planes  [T1 swizzle]
//   k_transpose: v -> vT [B][E][S] fp16
//   SINGLE group (all 8 batches):
//     k_scores: 0.125 * qh@kh^T -> fp16 scores [B][S][S]          [T1 swizzle]
//     k_softmax: row softmax (f32 math, fp16 in/out), P in-place + 1/rowsum
//     k_pv: (P @ vT^T) * recip -> attn_out fp16 + f32 amax        [T1 swizzle]
//   quant attn_out -> int8 -> exact i8 MFMA final proj -> d_out   [T1 swizzle]
// Round-7: __launch_bounds__(256,4) on all GEMMs (was ,2). VGPR 60-76 and
// 33KB LDS allow 4 blocks/CU; cross-block TLP is the only thing hiding the
// 2-phase barrier drain (r6 profile: Occupancy 21%, nothing saturated).
// Peak workspace ~196 MiB (proven).
// ---------------------------------------------------------------------------

typedef __attribute__((ext_vector_type(4))) float f32x4;
typedef __attribute__((ext_vector_type(4))) int i32x4;
typedef __attribute__((ext_vector_type(8))) char s8x8;
typedef _Float16 f16;
typedef _Float16 half8 __attribute__((ext_vector_type(8)));

#define DEVI static __device__ __forceinline__

constexpr int B_ = 8, S_ = 2048, E_ = 1024;
constexpr long NROW = (long)B_ * S_;  // 16384

constexpr size_t KB = 1024, MB = 1024 * 1024;
constexpr size_t OFF_SC  = 0;                     // u32[8] amax bits
constexpr size_t OFF_RS  = 1 * KB;                // 16384 f32 recip rowsums (64 KiB)
constexpr size_t OFF_W   = 128 * KB;              // 4 weight planes int8, 1 MiB each
constexpr size_t SZ_WPL  = (size_t)E_ * E_;       // 1 MiB
constexpr size_t SZ_PL   = (size_t)NROW * E_ * 2; // 32 MiB (fp16 plane)
constexpr size_t OFF_QH  = OFF_W + 4 * SZ_WPL;
constexpr size_t OFF_KH  = OFF_QH + SZ_PL;
constexpr size_t OFF_VH  = OFF_KH + SZ_PL;        // later overlay: attn_out fp16
constexpr size_t OFF_VT  = OFF_VH + SZ_PL;        // V^T fp16 [B][E][S]
constexpr size_t OFF_SCB = OFF_VT + SZ_PL;        // scores fp16 [B][S][S], 64 MiB
constexpr size_t WS_NEED = OFF_SCB + 64 * MB;     // ~196.1 MiB
constexpr size_t OFF_AOQ = OFF_SCB;               // int8 attn_out (16 MiB overlay)

// ---- helpers ---------------------------------------------------------------
typedef const __attribute__((address_space(1))) void* gptr1;
typedef __attribute__((address_space(3))) void* lptr3;

DEVI void gload16(const void* g, void* l) {
  __builtin_amdgcn_global_load_lds((gptr1)g, (lptr3)l, 16, 0, 0);
}

DEVI f32x4 MF16(half8 a, half8 b, f32x4 c) {
  return __builtin_amdgcn_mfma_f32_16x16x32_f16(a, b, c, 0, 0, 0);
}
DEVI i32x4 MFI8(i32x4 a, i32x4 b, i32x4 c) {
  return __builtin_amdgcn_mfma_i32_16x16x64_i8(a, b, c, 0, 0, 0);
}

DEVI float scale_of(const unsigned int* amaxU, int idx) {
  return fmaxf(__uint_as_float(amaxU[idx]) / 127.f, 1e-8f);
}

DEVI signed char q8(float x, float s) {  // true division: bit-exact vs reference
  return (signed char)(int)fminf(fmaxf(rintf(x / s), -127.f), 127.f);
}

// T1 XCD-chunked swizzle: hardware id d (round-robin over 8 XCDs) -> work id w
DEVI int xcd_swz(int d, int n) { return (d & 7) * (n >> 3) + (d >> 3); }

// wave reduce-max then ONE atomic per block via LDS (r4 lesson: 12288
// same-line wave-atomics serialized ~169us)
DEVI void block_atomic_max(float m, unsigned int* dst) {
  __shared__ float red[4];
#pragma unroll
  for (int o = 32; o; o >>= 1) m = fmaxf(m, __shfl_xor(m, o));
  const int lane = threadIdx.x & 63, wid = threadIdx.x >> 6;
  if (lane == 0) red[wid] = m;
  __syncthreads();
  if (threadIdx.x == 0) {
    m = fmaxf(fmaxf(red[0], red[1]), fmaxf(red[2], red[3]));
    atomicMax(dst, __float_as_uint(m));
  }
}

// ---- small kernels ---------------------------------------------------------
__global__ void k_zero(float* o, long n) {
  long i = ((long)blockIdx.x * blockDim.x + threadIdx.x) * 4;
  const long stride = (long)gridDim.x * blockDim.x * 4;
  for (; i < n; i += stride) {
    float4 z = {0.f, 0.f, 0.f, 0.f};
    *(float4*)(o + i) = z;
  }
}

__global__ void k_init(unsigned int* a) {
  if (threadIdx.x < 8) a[threadIdx.x] = 0u;
}

DEVI void amax_body(const float* __restrict__ x, long n, unsigned int* amaxU, int idx) {
  long i = ((long)blockIdx.x * blockDim.x + threadIdx.x) * 8;
  const long stride = (long)gridDim.x * blockDim.x * 8;
  float m = 0.f;
  for (; i < n; i += stride) {
    float4 a = *(const float4*)(x + i);
    float4 b = *(const float4*)(x + i + 4);
    m = fmaxf(m, fmaxf(fmaxf(fabsf(a.x), fabsf(a.y)), fmaxf(fabsf(a.z), fabsf(a.w))));
    m = fmaxf(m, fmaxf(fmaxf(fabsf(b.x), fabsf(b.y)), fmaxf(fabsf(b.z), fabsf(b.w))));
  }
  block_atomic_max(m, amaxU + idx);
}

__global__ void k_amax_in(const float* __restrict__ q, const float* __restrict__ k,
                          const float* __restrict__ v, long n, unsigned int* amaxU) {
  const int z = blockIdx.z;
  amax_body(z == 0 ? q : (z == 1 ? k : v), n, amaxU, z);
}
__global__ void k_amax_w(const float* __restrict__ a, const float* __restrict__ b,
                         const float* __restrict__ c, const float* __restrict__ d,
                         long n, unsigned int* amaxU) {
  const int z = blockIdx.z;
  amax_body(z == 0 ? a : (z == 1 ? b : (z == 2 ? c : d)), n, amaxU, 3 + z);
}

DEVI void quant8_body(const float* __restrict__ x, signed char* __restrict__ q, long n,
                      float s) {
  long i = ((long)blockIdx.x * blockDim.x + threadIdx.x) * 8;
  const long stride = (long)gridDim.x * blockDim.x * 8;
  for (; i < n; i += stride) {
    float4 a = *(const float4*)(x + i);
    float4 b = *(const float4*)(x + i + 4);
    s8x8 o;
    o[0] = q8(a.x, s); o[1] = q8(a.y, s); o[2] = q8(a.z, s); o[3] = q8(a.w, s);
    o[4] = q8(b.x, s); o[5] = q8(b.y, s); o[6] = q8(b.z, s); o[7] = q8(b.w, s);
    *(s8x8*)(q + i) = o;
  }
}

__global__ void k_quant_in(const float* __restrict__ q, const float* __restrict__ k,
                           const float* __restrict__ v, signed char* __restrict__ out,
                           long n, const unsigned int* __restrict__ amaxU) {
  const int z = blockIdx.z;
  quant8_body(z == 0 ? q : (z == 1 ? k : v), out + (size_t)z * n, n, scale_of(amaxU, z));
}
__global__ void k_quant_w(const float* __restrict__ a, const float* __restrict__ b,
                          const float* __restrict__ c, const float* __restrict__ d,
                          signed char* __restrict__ out, long n,
                          const unsigned int* __restrict__ amaxU) {
  const int z = blockIdx.z;
  quant8_body(z == 0 ? a : (z == 1 ? b : (z == 2 ? c : d)), out + (size_t)z * n, n,
              scale_of(amaxU, 3 + z));
}

// attn_out fp16 -> int8
__global__ void k_quant8_f16(char* __restrict__ ws) {
  const unsigned int* amaxU = (const unsigned int*)(ws + OFF_SC);
  const float s = scale_of(amaxU, 7);
  const f16* x = (const f16*)(ws + OFF_VH);
  signed char* o = (signed char*)(ws + OFF_AOQ);
  const long n = NROW * E_;
  long i = ((long)blockIdx.x * blockDim.x + threadIdx.x) * 8;
  const long stride = (long)gridDim.x * blockDim.x * 8;
  for (; i < n; i += stride) {
    half8 v = *(const half8*)(x + i);
    s8x8 w;
#pragma unroll
    for (int j = 0; j < 8; ++j) w[j] = q8((float)v[j], s);
    *(s8x8*)(o + i) = w;
  }
}

// ---- i8 GEMM core: C(128x128) = A(128xK)i8 @ B(128xK)i8^T, BK=128 ----------
DEVI void gemm_core_i8(const signed char* __restrict__ A, const signed char* __restrict__ Bm,
                       int lda, int K, signed char* ldsA, signed char* ldsB,
                       i32x4 acc[4][4], int tid) {
  const int lane = tid & 63, wid = tid >> 6;
  const int wm = wid >> 1, wn = wid & 1;
  const int frow = lane & 15;
  const int fko = (lane >> 4) * 16;
  for (int k0 = 0; k0 < K; k0 += 128) {
    __syncthreads();
#pragma unroll
    for (int it = 0; it < 4; ++it) {
      int c = it * 256 + tid;
      int row = c >> 3, cc = c & 7;
      int lb = (it * 256 + (tid & 192)) * 16;
      gload16(A + (long)row * lda + k0 + cc * 16, ldsA + lb);
      gload16(Bm + (long)row * lda + k0 + cc * 16, ldsB + lb);
    }
    __syncthreads();
#pragma unroll
    for (int kc = 0; kc < 2; ++kc) {
      i32x4 a[4], b[4];
#pragma unroll
      for (int m = 0; m < 4; ++m)
        a[m] = *(const i32x4*)(ldsA + (wm * 64 + m * 16 + frow) * 128 + kc * 64 + fko);
#pragma unroll
      for (int n = 0; n < 4; ++n)
        b[n] = *(const i32x4*)(ldsB + (wn * 64 + n * 16 + frow) * 128 + kc * 64 + fko);
#pragma unroll
      for (int m = 0; m < 4; ++m)
#pragma unroll
        for (int n = 0; n < 4; ++n)
          acc[m][n] = MFI8(a[m], b[n], acc[m][n]);
    }
  }
}

// ---- fp16 GEMM core: C(128x128) = A(128xK) @ B(128xK)^T, BK=64 -------------
DEVI void gemm_core_f16(const unsigned short* __restrict__ A,
                        const unsigned short* __restrict__ Bm, int lda, int ldb, int K,
                        unsigned short* ldsA, unsigned short* ldsB, f32x4 acc[4][4], int tid) {
  const int lane = tid & 63, wid = tid >> 6;
  const int wm = wid >> 1, wn = wid & 1;
  const int frow = lane & 15;
  const int fko = (lane >> 4) * 8;
  for (int k0 = 0; k0 < K; k0 += 64) {
    __syncthreads();
#pragma unroll
    for (int it = 0; it < 4; ++it) {
      int c = it * 256 + tid;
      int row = c >> 3, cc = c & 7;
      int lb = (it * 256 + (tid & 192)) * 8;
      gload16(A + (long)row * lda + k0 + cc * 8, ldsA + lb);
      gload16(Bm + (long)row * ldb + k0 + cc * 8, ldsB + lb);
    }
    __syncthreads();
#pragma unroll
    for (int kc = 0; kc < 2; ++kc) {
      half8 a[4], b[4];
#pragma unroll
      for (int m = 0; m < 4; ++m)
        a[m] = *(const half8*)(ldsA + (wm * 64 + m * 16 + frow) * 64 + kc * 32 + fko);
#pragma unroll
      for (int n = 0; n < 4; ++n)
        b[n] = *(const half8*)(ldsB + (wn * 64 + n * 16 + frow) * 64 + kc * 32 + fko);
#pragma unroll
      for (int m = 0; m < 4; ++m)
#pragma unroll
        for (int n = 0; n < 4; ++n)
          acc[m][n] = MF16(a[m], b[n], acc[m][n]);
    }
  }
}

// ---- projections: exact i8 GEMM -> fp16 planes -----------------------------
__global__ __launch_bounds__(256, 4) void k_proj_i8(char* __restrict__ ws,
                                                    const signed char* __restrict__ qi,
                                                    const float* __restrict__ bq,
                                                    const float* __restrict__ bk,
                                                    const float* __restrict__ bv) {
  __shared__ __attribute__((aligned(16))) signed char lA[128 * 128], lB[128 * 128];
  const int tid = threadIdx.x;
  int d = blockIdx.x + 8 * blockIdx.y + 1024 * blockIdx.z;
  int w = xcd_swz(d, 3072);
  const int bx = w & 7, by = (w >> 3) & 127, z = w >> 10;
  const unsigned int* amaxU = (const unsigned int*)(ws + OFF_SC);
  const signed char* A = qi + (size_t)z * NROW * E_ + (size_t)by * 128 * E_;
  const signed char* Bm =
      (const signed char*)(ws + OFF_W + (size_t)z * SZ_WPL) + (size_t)bx * 128 * E_;
  f16* H = (f16*)(ws + OFF_QH + (size_t)z * SZ_PL);
  const float* bias = (z == 0) ? bq : ((z == 1) ? bk : bv);
  const float sc = scale_of(amaxU, z) * scale_of(amaxU, 3 + z);
  i32x4 acc[4][4] = {};
  gemm_core_i8(A, Bm, E_, E_, lA, lB, acc, tid);
  const int lane = tid & 63, wid = tid >> 6, wm = wid >> 1, wn = wid & 1;
  const long r0 = (long)by * 128 + wm * 64;
  const int c0 = bx * 128 + wn * 64;
#pragma unroll
  for (int m = 0; m < 4; ++m)
#pragma unroll
    for (int n = 0; n < 4; ++n) {
      int col = c0 + n * 16 + (lane & 15);
      float bc = bias[col];
#pragma unroll
      for (int r = 0; r < 4; ++r) {
        long row = r0 + m * 16 + (lane >> 4) * 4 + r;
        H[row * E_ + col] = (f16)(sc * (float)acc[m][n][r] + bc);
      }
    }
}

// ---- V transpose: vh [b][s][e] -> vT [b][e][s] -----------------------------
__global__ void k_transpose(char* __restrict__ ws) {
  __shared__ f16 t[64][72];
  const int b = blockIdx.z, e0 = blockIdx.x * 64, s0 = blockIdx.y * 64;
  const f16* V = (const f16*)(ws + OFF_VH) + (size_t)b * S_ * E_;
  f16* VT = (f16*)(ws + OFF_VT) + (size_t)b * E_ * S_;
  const int tid = threadIdx.x;
  const int r = tid >> 2, cc = (tid & 3) * 16;
#pragma unroll
  for (int j = 0; j < 2; ++j) {
    half8 v = *(const half8*)(V + (size_t)(s0 + r) * E_ + e0 + cc + j * 8);
#pragma unroll
    for (int q = 0; q < 8; ++q) t[cc + j * 8 + q][r] = v[q];
  }
  __syncthreads();
#pragma unroll
  for (int j = 0; j < 2; ++j) {
    half8 w;
#pragma unroll
    for (int q = 0; q < 8; ++q) w[q] = t[r][cc + j * 8 + q];
    *(half8*)(VT + (size_t)(e0 + r) * S_ + s0 + cc + j * 8) = w;
  }
}

// ---- scores (all batches): S = 0.125 * qh@kh^T -> fp16 ---------------------
__global__ __launch_bounds__(256, 4) void k_scores(char* __restrict__ ws) {
  __shared__ __attribute__((aligned(16))) unsigned short lA[128 * 64], lB[128 * 64];
  const int tid = threadIdx.x;
  int d = blockIdx.x + 16 * blockIdx.y + 256 * blockIdx.z;
  int w = xcd_swz(d, 2048);
  const int bx = w & 15, by = (w >> 4) & 15, b = w >> 8;
  const unsigned short* A =
      (const unsigned short*)(ws + OFF_QH) + ((size_t)b * S_ + (size_t)by * 128) * E_;
  const unsigned short* Bm =
      (const unsigned short*)(ws + OFF_KH) + ((size_t)b * S_ + (size_t)bx * 128) * E_;
  f16* C = (f16*)(ws + OFF_SCB) + (size_t)b * S_ * S_;
  f32x4 acc[4][4] = {};
  gemm_core_f16(A, Bm, E_, E_, E_, lA, lB, acc, tid);
  const int lane = tid & 63, wid = tid >> 6, wm = wid >> 1, wn = wid & 1;
  const int r0 = by * 128 + wm * 64;
  const int c0 = bx * 128 + wn * 64;
#pragma unroll
  for (int m = 0; m < 4; ++m)
#pragma unroll
    for (int n = 0; n < 4; ++n) {
      int col = c0 + n * 16 + (lane & 15);
#pragma unroll
      for (int r = 0; r < 4; ++r) {
        int row = r0 + m * 16 + (lane >> 4) * 4 + r;
        C[(size_t)row * S_ + col] = (f16)(0.125f * acc[m][n][r]);
      }
    }
}

// ---- row softmax (all batches): fp16 in/out, f32 math, P in-place + 1/sum --
__global__ __launch_bounds__(256) void k_softmax(char* __restrict__ ws) {
  const long row = blockIdx.x;  // 0..16383
  f16* src = (f16*)(ws + OFF_SCB) + row * S_;
  float* RS = (float*)(ws + OFF_RS);
  const int tid = threadIdx.x, lane = tid & 63, wid = tid >> 6;
  half8 v = *(const half8*)(src + (long)tid * 8);
  float x[8];
#pragma unroll
  for (int j = 0; j < 8; ++j) x[j] = (float)v[j];
  float m = x[0];
#pragma unroll
  for (int j = 1; j < 8; ++j) m = fmaxf(m, x[j]);
#pragma unroll
  for (int o = 32; o; o >>= 1) m = fmaxf(m, __shfl_xor(m, o));
  __shared__ float redm[4], reds[4];
  if (lane == 0) redm[wid] = m;
  __syncthreads();
  m = fmaxf(fmaxf(redm[0], redm[1]), fmaxf(redm[2], redm[3]));
  float e[8], s = 0.f;
#pragma unroll
  for (int j = 0; j < 8; ++j) {
    e[j] = expf(x[j] - m);
    s += e[j];
  }
#pragma unroll
  for (int o = 32; o; o >>= 1) s += __shfl_xor(s, o);
  if (lane == 0) reds[wid] = s;
  __syncthreads();
  s = (reds[0] + reds[1]) + (reds[2] + reds[3]);
  if (tid == 0) RS[row] = 1.f / s;
  half8 p;
#pragma unroll
  for (int j = 0; j < 8; ++j) p[j] = (f16)e[j];
  *(half8*)(src + (long)tid * 8) = p;
}

// ---- PV (all batches): attn_out = (P @ vT^T) * recip -> fp16 + f32 amax ----
__global__ __launch_bounds__(256, 4) void k_pv(char* __restrict__ ws) {
  __shared__ __attribute__((aligned(16))) unsigned short lA[128 * 64], lB[128 * 64];
  const int tid = threadIdx.x;
  int d = blockIdx.x + 8 * blockIdx.y + 128 * blockIdx.z;
  int w = xcd_swz(d, 1024);
  const int bx = w & 7, by = (w >> 3) & 15, b = w >> 7;
  const unsigned short* A = (const unsigned short*)(ws + OFF_SCB) + (size_t)b * S_ * S_ +
                            (size_t)by * 128 * S_;
  const unsigned short* Bm = (const unsigned short*)(ws + OFF_VT) + (size_t)b * E_ * S_ +
                             (size_t)bx * 128 * S_;
  f32x4 acc[4][4] = {};
  gemm_core_f16(A, Bm, S_, S_, S_, lA, lB, acc, tid);
  const float* RS = (const float*)(ws + OFF_RS) + (size_t)b * S_;
  f16* O = (f16*)(ws + OFF_VH) + (size_t)b * S_ * E_;
  unsigned int* amaxU = (unsigned int*)(ws + OFF_SC);
  const int lane = tid & 63, wid = tid >> 6, wm = wid >> 1, wn = wid & 1;
  const int r0 = by * 128 + wm * 64;
  const int c0 = bx * 128 + wn * 64;
  float mx = 0.f;
#pragma unroll
  for (int m = 0; m < 4; ++m)
#pragma unroll
    for (int n = 0; n < 4; ++n) {
      int col = c0 + n * 16 + (lane & 15);
#pragma unroll
      for (int r = 0; r < 4; ++r) {
        int row = r0 + m * 16 + (lane >> 4) * 4 + r;
        float o = acc[m][n][r] * RS[row];
        O[(size_t)row * E_ + col] = (f16)o;
        mx = fmaxf(mx, fabsf(o));
      }
    }
  __syncthreads();  // lA/lB done; shared red[] in helper is fresh
  block_atomic_max(mx, amaxU + 7);
}

// ---- final projection: exact i8 GEMM -> d_out f32 --------------------------
__global__ __launch_bounds__(256, 4) void k_final_i8(char* __restrict__ ws,
                                                     const float* __restrict__ bp,
                                                     float* __restrict__ out) {
  __shared__ __attribute__((aligned(16))) signed char lA[128 * 128], lB[128 * 128];
  const int tid = threadIdx.x;
  int d = blockIdx.x + 8 * blockIdx.y;
  int w = xcd_swz(d, 1024);
  const int bx = w & 7, by = w >> 3;
  const unsigned int* amaxU = (const unsigned int*)(ws + OFF_SC);
  const signed char* A = (const signed char*)(ws + OFF_AOQ) + (size_t)by * 128 * E_;
  const signed char* Bm =
      (const signed char*)(ws + OFF_W + 3 * SZ_WPL) + (size_t)bx * 128 * E_;
  const float sc = scale_of(amaxU, 7) * scale_of(amaxU, 6);
  i32x4 acc[4][4] = {};
  gemm_core_i8(A, Bm, E_, E_, lA, lB, acc, tid);
  const int lane = tid & 63, wid = tid >> 6, wm = wid >> 1, wn = wid & 1;
  const long r0 = (long)by * 128 + wm * 64;
  const int c0 = bx * 128 + wn * 64;
#pragma unroll
  for (int m = 0; m < 4; ++m)
#pragma unroll
    for (int n = 0; n < 4; ++n) {
      int col = c0 + n * 16 + (lane & 15);
      float bc = bp[col];
#pragma unroll
      for (int r = 0; r < 4; ++r) {
        long row = r0 + m * 16 + (lane >> 4) * 4 + r;
        out[row * E_ + col] = sc * (float)acc[m][n][r] + bc;
      }
    }
}

// ---------------------------------------------------------------------------
extern "C" void kernel_launch(void* const* d_in, const int* in_sizes, int n_in,
                              void* d_out, int out_size, void* d_ws, size_t ws_size,
                              hipStream_t stream) {
  (void)in_sizes; (void)n_in; (void)out_size;
  char* ws = (char*)d_ws;
  const float* query = (const float*)d_in[0];
  const float* key   = (const float*)d_in[1];
  const float* value = (const float*)d_in[2];
  const float* Wq = (const float*)d_in[3];
  const float* bq = (const float*)d_in[4];
  const float* Wk = (const float*)d_in[5];
  const float* bk = (const float*)d_in[6];
  const float* Wv = (const float*)d_in[7];
  const float* bv = (const float*)d_in[8];
  const float* Wp = (const float*)d_in[9];
  const float* bp = (const float*)d_in[10];

  const long nIn = NROW * E_;  // 16,777,216
  const long nW = (long)E_ * E_;

  if (ws_size < WS_NEED) {  // diagnostic fallback: zeros, no OOB writes
    k_zero<<<dim3(2048), dim3(256), 0, stream>>>((float*)d_out, nIn);
    return;
  }

  unsigned int* amaxU = (unsigned int*)(ws + OFF_SC);
  signed char* qi = (signed char*)d_out;  // int8 q/k/v planes live in d_out

  k_init<<<dim3(1), dim3(64), 0, stream>>>(amaxU);
  k_amax_in<<<dim3(512, 1, 3), dim3(256), 0, stream>>>(query, key, value, nIn, amaxU);
  k_amax_w<<<dim3(64, 1, 4), dim3(256), 0, stream>>>(Wq, Wk, Wv, Wp, nW, amaxU);
  k_quant_in<<<dim3(1024, 1, 3), dim3(256), 0, stream>>>(query, key, value, qi, nIn, amaxU);
  k_quant_w<<<dim3(128, 1, 4), dim3(256), 0, stream>>>(Wq, Wk, Wv, Wp,
                                                       (signed char*)(ws + OFF_W), nW, amaxU);

  k_proj_i8<<<dim3(8, 128, 3), dim3(256), 0, stream>>>(ws, qi, bq, bk, bv);
  k_transpose<<<dim3(16, 32, 8), dim3(256), 0, stream>>>(ws);

  k_scores<<<dim3(16, 16, 8), dim3(256), 0, stream>>>(ws);
  k_softmax<<<dim3(16384), dim3(256), 0, stream>>>(ws);
  k_pv<<<dim3(8, 16, 8), dim3(256), 0, stream>>>(ws);

  k_quant8_f16<<<dim3(1024), dim3(256), 0, stream>>>(ws);
  k_final_i8<<<dim3(8, 128), dim3(256), 0, stream>>>(ws, bp, (float*)d_out);
}